// Round 12
// baseline (1494.701 us; speedup 1.0000x reference)
//
#include <hip/hip_runtime.h>
#include <hip/hip_bf16.h>
#include <math.h>

typedef __attribute__((ext_vector_type(8))) short short8;
typedef __attribute__((ext_vector_type(4))) float f32x4;

#define MFMA16(a,b,c) __builtin_amdgcn_mfma_f32_16x16x32_bf16((a),(b),(c),0,0,0)

__device__ __forceinline__ unsigned short f2bf(float f){
  unsigned int u = __builtin_bit_cast(unsigned int, f);
  u += 0x7fffu + ((u >> 16) & 1u);
  return (unsigned short)(u >> 16);
}
__device__ __forceinline__ unsigned short f2bf_rn(float f){
  unsigned int u = __builtin_bit_cast(unsigned int, f);
  return (unsigned short)((u + 0x8000u) >> 16);
}
__device__ __forceinline__ float bf2f(unsigned short u){
  unsigned int v = ((unsigned int)u) << 16;
  return __builtin_bit_cast(float, v);
}

__device__ __forceinline__ void gload16(const void* g, void* lds){
  __builtin_amdgcn_global_load_lds(
      (const __attribute__((address_space(1))) unsigned int*)g,
      (__attribute__((address_space(3))) unsigned int*)lds, 16, 0, 0);
}

// ---------------- weight transpose + cast: in [K][N] f32 -> out [N][K] bf16 ----------------
__global__ __launch_bounds__(256) void k_transpose_cast(const float* __restrict__ in,
    unsigned short* __restrict__ out, int K, int N)
{
  __shared__ unsigned short tile[32][33];
  const int tx = threadIdx.x, ty = threadIdx.y;
  const int n0 = blockIdx.x * 32, k0 = blockIdx.y * 32;
  #pragma unroll
  for (int i = 0; i < 4; i++) {
    int k = k0 + ty + i*8;
    tile[ty + i*8][tx] = f2bf(in[(size_t)k * N + n0 + tx]);
  }
  __syncthreads();
  #pragma unroll
  for (int i = 0; i < 4; i++) {
    int n = n0 + ty + i*8;
    out[(size_t)n * K + k0 + tx] = tile[tx][ty + i*8];
  }
}

// ---------------- layernorm: x [rows][1024] (f32 or bf16) -> out bf16 ----------------
template<int BF16IN>
__global__ __launch_bounds__(256) void k_layernorm(const void* __restrict__ xin,
    const float* __restrict__ g, const float* __restrict__ b,
    unsigned short* __restrict__ out)
{
  const int row = blockIdx.x;
  const int t = threadIdx.x;
  float4 v;
  if (BF16IN) {
    const ushort4 u = ((const ushort4*)((const unsigned short*)xin + (size_t)row * 1024))[t];
    v.x = bf2f(u.x); v.y = bf2f(u.y); v.z = bf2f(u.z); v.w = bf2f(u.w);
  } else {
    v = ((const float4*)((const float*)xin + (size_t)row * 1024))[t];
  }
  float s  = v.x + v.y + v.z + v.w;
  float s2 = v.x*v.x + v.y*v.y + v.z*v.z + v.w*v.w;
  #pragma unroll
  for (int m = 1; m < 64; m <<= 1) {
    s  += __shfl_xor(s,  m);
    s2 += __shfl_xor(s2, m);
  }
  __shared__ float red[2][4];
  const int wid = t >> 6, lane = t & 63;
  if (lane == 0) { red[0][wid] = s; red[1][wid] = s2; }
  __syncthreads();
  s  = red[0][0] + red[0][1] + red[0][2] + red[0][3];
  s2 = red[1][0] + red[1][1] + red[1][2] + red[1][3];
  const float mu = s * (1.0f / 1024.0f);
  const float var = s2 * (1.0f / 1024.0f) - mu * mu;
  const float rstd = rsqrtf(var + 1e-6f);
  const float4 gv = ((const float4*)g)[t];
  const float4 bv = ((const float4*)b)[t];
  ushort4 o;
  o.x = f2bf((v.x - mu) * rstd * gv.x + bv.x);
  o.y = f2bf((v.y - mu) * rstd * gv.y + bv.y);
  o.z = f2bf((v.z - mu) * rstd * gv.z + bv.z);
  o.w = f2bf((v.w - mu) * rstd * gv.w + bv.w);
  ((ushort4*)(out + (size_t)row * 1024))[t] = o;
}

// ---------------- 128x128 MFMA GEMM — m97 structure, BK=64, conflict-free swizzle ----------
// C[M][N] = A[M][K](bf16) * Bt[N][K]^T(bf16) + epilogue
// EPI 0: QKV: bn<16 -> qk (stride 2048) bf16; bn>=16 -> vT[b][h][d][n] bf16
// EPI 1: out bf16 = gelu(acc + bias)
// EPI 2: out bf16 = resid(f32) + (acc+bias)*lsg      (proj -> x1 bf16)
// EPI 3: out f32  = resid(bf16) + (acc+bias)*lsg     (fc2 -> d_out f32)
// launch_bounds(256,4): 4 blocks/CU (VGPR 80<=128, LDS 4x32KB=128<=160KB);
// FC2/proj grids (1024) are exactly one residency wave -> zero tail.
template<int EPI>
__global__ __launch_bounds__(256, 4) void k_gemm128(
    const unsigned short* __restrict__ A,
    const unsigned short* __restrict__ Bt,
    const float* __restrict__ bias,
    const void* __restrict__ resid,
    const float* __restrict__ lsg,
    void* __restrict__ outp,
    unsigned short* __restrict__ vtp,
    int M, int N, int K, int nbn)
{
  __shared__ __align__(16) unsigned short Asm[128 * 64];   // 16 KB
  __shared__ __align__(16) unsigned short Bsm[128 * 64];   // 16 KB

  const int bid = blockIdx.x;
  const int mrows = (gridDim.x >> 3) / nbn;
  const int xcd = bid & 7, l = bid >> 3;
  const int bm = xcd * mrows + (l % mrows);
  const int bn = l / mrows;

  const int t = threadIdx.x, lane = t & 63;
  const int wid = t >> 6, wm = wid >> 1, wn = wid & 1;
  const int fr = lane & 15, fg = lane >> 4;

  size_t aOf[4], bOf[4];
  int dOf[4];
  #pragma unroll
  for (int i = 0; i < 4; i++) {
    const int s = i * 256 + t;
    const int row = s >> 3, c = s & 7;
    const int cs = c ^ (row & 7);
    dOf[i] = s * 16;
    aOf[i] = ((size_t)bm * 128 + row) * K + cs * 8;
    bOf[i] = ((size_t)bn * 128 + row) * K + cs * 8;
  }

  f32x4 acc[4][4] = {};

  for (int kt = 0; kt < K; kt += 64) {
    __syncthreads();
    #pragma unroll
    for (int i = 0; i < 4; i++) gload16(A  + aOf[i] + kt, (char*)Asm + dOf[i]);
    #pragma unroll
    for (int i = 0; i < 4; i++) gload16(Bt + bOf[i] + kt, (char*)Bsm + dOf[i]);
    __syncthreads();

    short8 af[4][2], bfv[4][2];
    #pragma unroll
    for (int m = 0; m < 4; m++) {
      const int row = wm * 64 + m * 16 + fr;
      const char* p = (const char*)Asm + row * 128;
      af[m][0] = *(const short8*)(p + ((fg       ^ (row & 7)) * 16));
      af[m][1] = *(const short8*)(p + (((4 + fg) ^ (row & 7)) * 16));
    }
    #pragma unroll
    for (int n = 0; n < 4; n++) {
      const int row = wn * 64 + n * 16 + fr;
      const char* p = (const char*)Bsm + row * 128;
      bfv[n][0] = *(const short8*)(p + ((fg       ^ (row & 7)) * 16));
      bfv[n][1] = *(const short8*)(p + (((4 + fg) ^ (row & 7)) * 16));
    }
    __builtin_amdgcn_s_setprio(1);
    #pragma unroll
    for (int kk = 0; kk < 2; kk++)
      #pragma unroll
      for (int m = 0; m < 4; m++)
        #pragma unroll
        for (int n = 0; n < 4; n++)
          acc[m][n] = MFMA16(af[m][kk], bfv[n][kk], acc[m][n]);
    __builtin_amdgcn_s_setprio(0);
  }

  const int row0 = bm * 128 + wm * 64 + fg * 4;
  const int col0 = bn * 128 + wn * 64 + fr;
  #pragma unroll
  for (int n = 0; n < 4; n++) {
    const int col = col0 + n * 16;
    const float bcol = bias[col];
    float lscale = 0.f;
    if (EPI >= 2) lscale = lsg[col];
    #pragma unroll
    for (int m = 0; m < 4; m++) {
      #pragma unroll
      for (int r = 0; r < 4; r++) {
        const int row = row0 + m * 16 + r;
        float v = acc[m][n][r] + bcol;
        if (EPI == 0) {
          if (bn < 16) {
            ((unsigned short*)outp)[(size_t)row * 2048 + col] = f2bf(v);
          } else {
            const int d = col - 2048, hh = d >> 6, dd = d & 63;
            const int bb = row >> 10, nn = row & 1023;
            vtp[(((size_t)bb * 16 + hh) * 64 + dd) * 1024 + nn] = f2bf(v);
          }
        } else if (EPI == 1) {
          const float u = v * (0.7978845608f + 0.0356774081f * v * v);
          v = v * __builtin_amdgcn_rcpf(1.0f + __expf(-2.0f * u));
          ((unsigned short*)outp)[(size_t)row * N + col] = f2bf(v);
        } else if (EPI == 2) {
          const float rv = ((const float*)resid)[(size_t)row * N + col];
          ((unsigned short*)outp)[(size_t)row * N + col] = f2bf(rv + v * lscale);
        } else {
          const float rv = bf2f(((const unsigned short*)resid)[(size_t)row * N + col]);
          ((float*)outp)[(size_t)row * N + col] = rv + v * lscale;
        }
      }
    }
  }
}

// ---------------- flash attention (no 1/sqrt(d) scale, faithful to ref) ----------------
// qk: [16384][2048] bf16 ; vT: [b][h][64 d][1024 n] bf16 ; out: [16384][1024] bf16
// T14 async-STAGE: per-lane uint4 global loads for tile t+1 issued BEFORE tile t's
// compute (reg loads don't force barrier drain); barrier -> vmcnt(0) -> ds_write
// -> barrier. HBM latency hides under QK+softmax+PV.
__global__ __launch_bounds__(512) void k_attn(const unsigned short* __restrict__ qk,
                                              const unsigned short* __restrict__ vT,
                                              unsigned short* __restrict__ out)
{
  const int bid = blockIdx.x;
  const int xcd = bid & 7, l = bid >> 3;
  const int bh = xcd * 32 + (l >> 2);
  const int qt = l & 3;
  const int b = bh >> 4, h = bh & 15;
  const int t = threadIdx.x, lane = t & 63, wid = t >> 6;
  const int fr = lane & 15, fg = lane >> 4;
  const int q0 = qt * 256 + wid * 32;

  __shared__ __align__(16) unsigned short Ksm[64 * 64];
  __shared__ __align__(16) unsigned short Vsm[64 * 64];
  __shared__ __align__(16) unsigned short plds[8][32][72];

  const size_t qbase = (size_t)b * 1024 * 2048 + (size_t)h * 64;
  const size_t kbase = qbase + 1024;
  const size_t vbase = (size_t)bh * 64 * 1024;

  short8 qf[2][2];
  #pragma unroll
  for (int m = 0; m < 2; m++)
    #pragma unroll
    for (int kh = 0; kh < 2; kh++)
      qf[m][kh] = *(const short8*)(qk + qbase + (size_t)(q0 + m*16 + fr) * 2048
                                   + kh*32 + fg*8);

  f32x4 oacc[2][4] = {};
  float mrow[2][4], lrow[2][4];
  #pragma unroll
  for (int m = 0; m < 2; m++)
    #pragma unroll
    for (int r = 0; r < 4; r++) { mrow[m][r] = -1e30f; lrow[m][r] = 0.f; }

  const int srow = t >> 3, sc = t & 7;
  const int scs = sc ^ (srow & 7);
  const unsigned short* kSrc = qk + kbase + (size_t)srow * 2048 + scs*8;
  const unsigned short* vSrc = vT + vbase + (size_t)srow * 1024 + scs*8;
  uint4* kDst = (uint4*)((char*)Ksm + t*16);
  uint4* vDst = (uint4*)((char*)Vsm + t*16);

  // prologue: stage tile 0
  {
    uint4 kr = *(const uint4*)kSrc;            // kv0 = 0
    uint4 vr = *(const uint4*)vSrc;
    *kDst = kr; *vDst = vr;
  }
  __syncthreads();

  for (int it = 0; it < 16; ++it) {
    const int kv0 = it * 64;
    // issue next-tile loads to registers (no wait)
    uint4 kr2, vr2;
    if (it < 15) {
      kr2 = *(const uint4*)(kSrc + (size_t)(kv0 + 64) * 2048);
      vr2 = *(const uint4*)(vSrc + kv0 + 64);
    }

    // ---- compute tile it from Ksm/Vsm ----
    f32x4 sacc[2][4] = {};
    #pragma unroll
    for (int n = 0; n < 4; n++) {
      #pragma unroll
      for (int kh = 0; kh < 2; kh++) {
        const int krow = n*16 + fr;
        short8 kf = *(const short8*)&Ksm[krow*64 + (((kh*4 + fg) ^ (krow & 7)) * 8)];
        sacc[0][n] = MFMA16(qf[0][kh], kf, sacc[0][n]);
        sacc[1][n] = MFMA16(qf[1][kh], kf, sacc[1][n]);
      }
    }

    #pragma unroll
    for (int m = 0; m < 2; m++) {
      float pm[4];
      #pragma unroll
      for (int r = 0; r < 4; r++)
        pm[r] = fmaxf(fmaxf(sacc[m][0][r], sacc[m][1][r]),
                      fmaxf(sacc[m][2][r], sacc[m][3][r]));
      #pragma unroll
      for (int msk = 1; msk < 16; msk <<= 1)
        #pragma unroll
        for (int r = 0; r < 4; r++) pm[r] = fmaxf(pm[r], __shfl_xor(pm[r], msk));

      int grow = 0;
      #pragma unroll
      for (int r = 0; r < 4; r++) grow |= (pm[r] > mrow[m][r] + 8.f) ? 1 : 0;
      if (__any(grow)) {
        #pragma unroll
        for (int r = 0; r < 4; r++) {
          const float mn = fmaxf(mrow[m][r], pm[r]);
          const float corr = __expf(mrow[m][r] - mn);
          mrow[m][r] = mn;
          lrow[m][r] *= corr;
          #pragma unroll
          for (int d16 = 0; d16 < 4; d16++) oacc[m][d16][r] *= corr;
        }
      }

      float psum[4] = {0.f, 0.f, 0.f, 0.f};
      #pragma unroll
      for (int n = 0; n < 4; n++)
        #pragma unroll
        for (int r = 0; r < 4; r++) {
          float p = __expf(sacc[m][n][r] - mrow[m][r]);
          sacc[m][n][r] = p;
          psum[r] += p;
        }
      #pragma unroll
      for (int msk = 1; msk < 16; msk <<= 1)
        #pragma unroll
        for (int r = 0; r < 4; r++) psum[r] += __shfl_xor(psum[r], msk);
      #pragma unroll
      for (int r = 0; r < 4; r++) lrow[m][r] += psum[r];
      #pragma unroll
      for (int n = 0; n < 4; n++)
        #pragma unroll
        for (int r = 0; r < 4; r++)
          plds[wid][m*16 + fg*4 + r][n*16 + fr] = f2bf_rn(sacc[m][n][r]);
    }

    short8 pf[2][2];
    #pragma unroll
    for (int m = 0; m < 2; m++)
      #pragma unroll
      for (int kh = 0; kh < 2; kh++)
        pf[m][kh] = *(const short8*)&plds[wid][m*16 + fr][kh*32 + fg*8];

    #pragma unroll
    for (int d16 = 0; d16 < 4; d16++) {
      #pragma unroll
      for (int kh = 0; kh < 2; kh++) {
        const int vrow = d16*16 + fr;
        short8 vf = *(const short8*)&Vsm[vrow*64 + (((kh*4 + fg) ^ (vrow & 7)) * 8)];
        oacc[0][d16] = MFMA16(pf[0][kh], vf, oacc[0][d16]);
        oacc[1][d16] = MFMA16(pf[1][kh], vf, oacc[1][d16]);
      }
    }

    // ---- swap in tile it+1 ----
    if (it < 15) {
      __syncthreads();                                   // all reads of Ksm/Vsm done
      asm volatile("s_waitcnt vmcnt(0)" ::: "memory");   // kr2/vr2 arrived
      *kDst = kr2; *vDst = vr2;
      __syncthreads();                                   // staged for next iter
    }
  }

  #pragma unroll
  for (int m = 0; m < 2; m++) {
    float inv[4];
    #pragma unroll
    for (int r = 0; r < 4; r++) inv[r] = 1.0f / lrow[m][r];
    #pragma unroll
    for (int d16 = 0; d16 < 4; d16++) {
      #pragma unroll
      for (int r = 0; r < 4; r++) {
        const int qrow = q0 + m*16 + fg*4 + r;
        const int col = h*64 + d16*16 + fr;
        out[(size_t)(b * 1024 + qrow) * 1024 + col] = f2bf(oacc[m][d16][r] * inv[r]);
      }
    }
  }
}

// ---------------- host launch ----------------
extern "C" void kernel_launch(void* const* d_in, const int* in_sizes, int n_in,
                              void* d_out, int out_size, void* d_ws, size_t ws_size,
                              hipStream_t stream) {
  const float* x      = (const float*)d_in[0];
  const float* ln1_g  = (const float*)d_in[1];
  const float* ln1_b  = (const float*)d_in[2];
  const float* qkv_w  = (const float*)d_in[3];
  const float* qkv_b  = (const float*)d_in[4];
  const float* proj_w = (const float*)d_in[5];
  const float* proj_b = (const float*)d_in[6];
  const float* ls1_g  = (const float*)d_in[7];
  const float* ln2_g  = (const float*)d_in[8];
  const float* ln2_b  = (const float*)d_in[9];
  const float* fc1_w  = (const float*)d_in[10];
  const float* fc1_b  = (const float*)d_in[11];
  const float* fc2_w  = (const float*)d_in[12];
  const float* fc2_b  = (const float*)d_in[13];
  const float* ls2_g  = (const float*)d_in[14];

  char* w = (char*)d_ws;
  unsigned short* wqkvT  = (unsigned short*)(w + 0);           //  6,291,456
  unsigned short* wprojT = (unsigned short*)(w + 6291456);     //  2,097,152
  unsigned short* wfc1T  = (unsigned short*)(w + 8388608);     //  8,388,608
  unsigned short* wfc2T  = (unsigned short*)(w + 16777216);    //  8,388,608
  unsigned short* x1     = (unsigned short*)(w + 25165824);    // 33,554,432 (bf16)
  unsigned short* h1     = (unsigned short*)(w + 58720256);    // 33,554,432
  unsigned short* qkbuf  = (unsigned short*)(w + 92274688);    // 67,108,864 [16384][2048]
  unsigned short* vtbuf  = (unsigned short*)(w + 159383552);   // 33,554,432 [256][64][1024]
  unsigned short* attno  = (unsigned short*)(w + 192937984);   // 33,554,432
  unsigned short* h3     = (unsigned short*)(w + 92274688);    // 134,217,728 (overlay)

  dim3 tb32(32, 8);
  k_transpose_cast<<<dim3(3072/32, 1024/32), tb32, 0, stream>>>(qkv_w,  wqkvT, 1024, 3072);
  k_transpose_cast<<<dim3(1024/32, 1024/32), tb32, 0, stream>>>(proj_w, wprojT, 1024, 1024);
  k_transpose_cast<<<dim3(4096/32, 1024/32), tb32, 0, stream>>>(fc1_w,  wfc1T, 1024, 4096);
  k_transpose_cast<<<dim3(1024/32, 4096/32), tb32, 0, stream>>>(fc2_w,  wfc2T, 4096, 1024);

  // LN1 (f32 in)
  k_layernorm<0><<<16384, 256, 0, stream>>>(x, ln1_g, ln1_b, h1);
  // QKV = h1 @ qkv_w + qkv_b ; Q,K -> qkbuf, V -> vtbuf transposed
  k_gemm128<0><<<128*24, 256, 0, stream>>>(h1, wqkvT, qkv_b, nullptr, nullptr,
                                           qkbuf, vtbuf, 16384, 3072, 1024, 24);
  // attention (XCD-grouped bh mapping)
  k_attn<<<1024, 512, 0, stream>>>(qkbuf, vtbuf, attno);
  // x1(bf16) = x(f32) + (attn @ proj_w + proj_b) * ls1_g
  k_gemm128<2><<<128*8, 256, 0, stream>>>(attno, wprojT, proj_b, x, ls1_g,
                                          x1, nullptr, 16384, 1024, 1024, 8);
  // LN2 (bf16 in)
  k_layernorm<1><<<16384, 256, 0, stream>>>(x1, ln2_g, ln2_b, h1);
  // h3 = gelu(h2 @ fc1_w + fc1_b)
  k_gemm128<1><<<128*32, 256, 0, stream>>>(h1, wfc1T, fc1_b, nullptr, nullptr,
                                           h3, nullptr, 16384, 4096, 1024, 32);
  // out(f32) = x1(bf16) + (h3 @ fc2_w + fc2_b) * ls2_g
  k_gemm128<3><<<128*8, 256, 0, stream>>>(h3, wfc2T, fc2_b, x1, ls2_g,
                                          (float*)d_out, nullptr, 16384, 1024, 4096, 8);
}

// Round 13
// 814.117 us; speedup vs baseline: 1.8360x; 1.8360x over previous
//
#include <hip/hip_runtime.h>
#include <hip/hip_bf16.h>
#include <math.h>

typedef __attribute__((ext_vector_type(8))) short short8;
typedef __attribute__((ext_vector_type(4))) float f32x4;

#define MFMA16(a,b,c) __builtin_amdgcn_mfma_f32_16x16x32_bf16((a),(b),(c),0,0,0)

__device__ __forceinline__ unsigned short f2bf(float f){
  unsigned int u = __builtin_bit_cast(unsigned int, f);
  u += 0x7fffu + ((u >> 16) & 1u);
  return (unsigned short)(u >> 16);
}
__device__ __forceinline__ unsigned short f2bf_rn(float f){
  unsigned int u = __builtin_bit_cast(unsigned int, f);
  return (unsigned short)((u + 0x8000u) >> 16);
}
__device__ __forceinline__ float bf2f(unsigned short u){
  unsigned int v = ((unsigned int)u) << 16;
  return __builtin_bit_cast(float, v);
}

__device__ __forceinline__ void gload16(const void* g, void* lds){
  __builtin_amdgcn_global_load_lds(
      (const __attribute__((address_space(1))) unsigned int*)g,
      (__attribute__((address_space(3))) unsigned int*)lds, 16, 0, 0);
}

// ---------------- weight transpose + cast: in [K][N] f32 -> out [N][K] bf16 ----------------
__global__ __launch_bounds__(256) void k_transpose_cast(const float* __restrict__ in,
    unsigned short* __restrict__ out, int K, int N)
{
  __shared__ unsigned short tile[32][33];
  const int tx = threadIdx.x, ty = threadIdx.y;
  const int n0 = blockIdx.x * 32, k0 = blockIdx.y * 32;
  #pragma unroll
  for (int i = 0; i < 4; i++) {
    int k = k0 + ty + i*8;
    tile[ty + i*8][tx] = f2bf(in[(size_t)k * N + n0 + tx]);
  }
  __syncthreads();
  #pragma unroll
  for (int i = 0; i < 4; i++) {
    int n = n0 + ty + i*8;
    out[(size_t)n * K + k0 + tx] = tile[tx][ty + i*8];
  }
}

// ---------------- layernorm: x [rows][1024] (f32 or bf16) -> out bf16 ----------------
template<int BF16IN>
__global__ __launch_bounds__(256) void k_layernorm(const void* __restrict__ xin,
    const float* __restrict__ g, const float* __restrict__ b,
    unsigned short* __restrict__ out)
{
  const int row = blockIdx.x;
  const int t = threadIdx.x;
  float4 v;
  if (BF16IN) {
    const ushort4 u = ((const ushort4*)((const unsigned short*)xin + (size_t)row * 1024))[t];
    v.x = bf2f(u.x); v.y = bf2f(u.y); v.z = bf2f(u.z); v.w = bf2f(u.w);
  } else {
    v = ((const float4*)((const float*)xin + (size_t)row * 1024))[t];
  }
  float s  = v.x + v.y + v.z + v.w;
  float s2 = v.x*v.x + v.y*v.y + v.z*v.z + v.w*v.w;
  #pragma unroll
  for (int m = 1; m < 64; m <<= 1) {
    s  += __shfl_xor(s,  m);
    s2 += __shfl_xor(s2, m);
  }
  __shared__ float red[2][4];
  const int wid = t >> 6, lane = t & 63;
  if (lane == 0) { red[0][wid] = s; red[1][wid] = s2; }
  __syncthreads();
  s  = red[0][0] + red[0][1] + red[0][2] + red[0][3];
  s2 = red[1][0] + red[1][1] + red[1][2] + red[1][3];
  const float mu = s * (1.0f / 1024.0f);
  const float var = s2 * (1.0f / 1024.0f) - mu * mu;
  const float rstd = rsqrtf(var + 1e-6f);
  const float4 gv = ((const float4*)g)[t];
  const float4 bv = ((const float4*)b)[t];
  ushort4 o;
  o.x = f2bf((v.x - mu) * rstd * gv.x + bv.x);
  o.y = f2bf((v.y - mu) * rstd * gv.y + bv.y);
  o.z = f2bf((v.z - mu) * rstd * gv.z + bv.z);
  o.w = f2bf((v.w - mu) * rstd * gv.w + bv.w);
  ((ushort4*)(out + (size_t)row * 1024))[t] = o;
}

// ---------------- 128x128 MFMA GEMM — m97 structure, BK=64, conflict-free swizzle ----------
// C[M][N] = A[M][K](bf16) * Bt[N][K]^T(bf16) + epilogue
// EPI 0: QKV: bn<16 -> qk (stride 2048) bf16; bn>=16 -> vT[b][h][d][n] bf16
// EPI 1: out bf16 = gelu(acc + bias)
// EPI 2: out bf16 = resid(f32) + (acc+bias)*lsg      (proj -> x1 bf16)
// EPI 3: out f32  = resid(bf16) + (acc+bias)*lsg     (fc2 -> d_out f32)
// launch_bounds(256,3): 3 blocks/CU. NOTE (r12 lesson): (256,4) caps VGPR at 64
// -> fragment spill to scratch (FETCH 195->572 MB, 2x slower). 3 is the max that
// fits the ~80 VGPR + 64 AGPR working set.
template<int EPI>
__global__ __launch_bounds__(256, 3) void k_gemm128(
    const unsigned short* __restrict__ A,
    const unsigned short* __restrict__ Bt,
    const float* __restrict__ bias,
    const void* __restrict__ resid,
    const float* __restrict__ lsg,
    void* __restrict__ outp,
    unsigned short* __restrict__ vtp,
    int M, int N, int K, int nbn)
{
  __shared__ __align__(16) unsigned short Asm[128 * 64];   // 16 KB
  __shared__ __align__(16) unsigned short Bsm[128 * 64];   // 16 KB

  const int bid = blockIdx.x;
  const int mrows = (gridDim.x >> 3) / nbn;
  const int xcd = bid & 7, l = bid >> 3;
  const int bm = xcd * mrows + (l % mrows);
  const int bn = l / mrows;

  const int t = threadIdx.x, lane = t & 63;
  const int wid = t >> 6, wm = wid >> 1, wn = wid & 1;
  const int fr = lane & 15, fg = lane >> 4;

  size_t aOf[4], bOf[4];
  int dOf[4];
  #pragma unroll
  for (int i = 0; i < 4; i++) {
    const int s = i * 256 + t;
    const int row = s >> 3, c = s & 7;
    const int cs = c ^ (row & 7);
    dOf[i] = s * 16;
    aOf[i] = ((size_t)bm * 128 + row) * K + cs * 8;
    bOf[i] = ((size_t)bn * 128 + row) * K + cs * 8;
  }

  f32x4 acc[4][4] = {};

  for (int kt = 0; kt < K; kt += 64) {
    __syncthreads();
    #pragma unroll
    for (int i = 0; i < 4; i++) gload16(A  + aOf[i] + kt, (char*)Asm + dOf[i]);
    #pragma unroll
    for (int i = 0; i < 4; i++) gload16(Bt + bOf[i] + kt, (char*)Bsm + dOf[i]);
    __syncthreads();

    short8 af[4][2], bfv[4][2];
    #pragma unroll
    for (int m = 0; m < 4; m++) {
      const int row = wm * 64 + m * 16 + fr;
      const char* p = (const char*)Asm + row * 128;
      af[m][0] = *(const short8*)(p + ((fg       ^ (row & 7)) * 16));
      af[m][1] = *(const short8*)(p + (((4 + fg) ^ (row & 7)) * 16));
    }
    #pragma unroll
    for (int n = 0; n < 4; n++) {
      const int row = wn * 64 + n * 16 + fr;
      const char* p = (const char*)Bsm + row * 128;
      bfv[n][0] = *(const short8*)(p + ((fg       ^ (row & 7)) * 16));
      bfv[n][1] = *(const short8*)(p + (((4 + fg) ^ (row & 7)) * 16));
    }
    __builtin_amdgcn_s_setprio(1);
    #pragma unroll
    for (int kk = 0; kk < 2; kk++)
      #pragma unroll
      for (int m = 0; m < 4; m++)
        #pragma unroll
        for (int n = 0; n < 4; n++)
          acc[m][n] = MFMA16(af[m][kk], bfv[n][kk], acc[m][n]);
    __builtin_amdgcn_s_setprio(0);
  }

  const int row0 = bm * 128 + wm * 64 + fg * 4;
  const int col0 = bn * 128 + wn * 64 + fr;
  #pragma unroll
  for (int n = 0; n < 4; n++) {
    const int col = col0 + n * 16;
    const float bcol = bias[col];
    float lscale = 0.f;
    if (EPI >= 2) lscale = lsg[col];
    #pragma unroll
    for (int m = 0; m < 4; m++) {
      #pragma unroll
      for (int r = 0; r < 4; r++) {
        const int row = row0 + m * 16 + r;
        float v = acc[m][n][r] + bcol;
        if (EPI == 0) {
          if (bn < 16) {
            ((unsigned short*)outp)[(size_t)row * 2048 + col] = f2bf(v);
          } else {
            const int d = col - 2048, hh = d >> 6, dd = d & 63;
            const int bb = row >> 10, nn = row & 1023;
            vtp[(((size_t)bb * 16 + hh) * 64 + dd) * 1024 + nn] = f2bf(v);
          }
        } else if (EPI == 1) {
          const float u = v * (0.7978845608f + 0.0356774081f * v * v);
          v = v * __builtin_amdgcn_rcpf(1.0f + __expf(-2.0f * u));
          ((unsigned short*)outp)[(size_t)row * N + col] = f2bf(v);
        } else if (EPI == 2) {
          const float rv = ((const float*)resid)[(size_t)row * N + col];
          ((unsigned short*)outp)[(size_t)row * N + col] = f2bf(rv + v * lscale);
        } else {
          const float rv = bf2f(((const unsigned short*)resid)[(size_t)row * N + col]);
          ((float*)outp)[(size_t)row * N + col] = rv + v * lscale;
        }
      }
    }
  }
}

// ---------------- flash attention (no 1/sqrt(d) scale, faithful to ref) ----------------
// qk: [16384][2048] bf16 ; vT: [b][h][64 d][1024 n] bf16 ; out: [16384][1024] bf16
// T14 async-STAGE: per-lane uint4 global loads for tile t+1 issued BEFORE tile t's
// compute; barrier -> vmcnt(0) -> ds_write -> barrier.
__global__ __launch_bounds__(512) void k_attn(const unsigned short* __restrict__ qk,
                                              const unsigned short* __restrict__ vT,
                                              unsigned short* __restrict__ out)
{
  const int bid = blockIdx.x;
  const int xcd = bid & 7, l = bid >> 3;
  const int bh = xcd * 32 + (l >> 2);
  const int qt = l & 3;
  const int b = bh >> 4, h = bh & 15;
  const int t = threadIdx.x, lane = t & 63, wid = t >> 6;
  const int fr = lane & 15, fg = lane >> 4;
  const int q0 = qt * 256 + wid * 32;

  __shared__ __align__(16) unsigned short Ksm[64 * 64];
  __shared__ __align__(16) unsigned short Vsm[64 * 64];
  __shared__ __align__(16) unsigned short plds[8][32][72];

  const size_t qbase = (size_t)b * 1024 * 2048 + (size_t)h * 64;
  const size_t kbase = qbase + 1024;
  const size_t vbase = (size_t)bh * 64 * 1024;

  short8 qf[2][2];
  #pragma unroll
  for (int m = 0; m < 2; m++)
    #pragma unroll
    for (int kh = 0; kh < 2; kh++)
      qf[m][kh] = *(const short8*)(qk + qbase + (size_t)(q0 + m*16 + fr) * 2048
                                   + kh*32 + fg*8);

  f32x4 oacc[2][4] = {};
  float mrow[2][4], lrow[2][4];
  #pragma unroll
  for (int m = 0; m < 2; m++)
    #pragma unroll
    for (int r = 0; r < 4; r++) { mrow[m][r] = -1e30f; lrow[m][r] = 0.f; }

  const int srow = t >> 3, sc = t & 7;
  const int scs = sc ^ (srow & 7);
  const unsigned short* kSrc = qk + kbase + (size_t)srow * 2048 + scs*8;
  const unsigned short* vSrc = vT + vbase + (size_t)srow * 1024 + scs*8;
  uint4* kDst = (uint4*)((char*)Ksm + t*16);
  uint4* vDst = (uint4*)((char*)Vsm + t*16);

  // prologue: stage tile 0
  {
    uint4 kr = *(const uint4*)kSrc;
    uint4 vr = *(const uint4*)vSrc;
    *kDst = kr; *vDst = vr;
  }
  __syncthreads();

  for (int it = 0; it < 16; ++it) {
    const int kv0 = it * 64;
    uint4 kr2, vr2;
    if (it < 15) {
      kr2 = *(const uint4*)(kSrc + (size_t)(kv0 + 64) * 2048);
      vr2 = *(const uint4*)(vSrc + kv0 + 64);
    }

    f32x4 sacc[2][4] = {};
    #pragma unroll
    for (int n = 0; n < 4; n++) {
      #pragma unroll
      for (int kh = 0; kh < 2; kh++) {
        const int krow = n*16 + fr;
        short8 kf = *(const short8*)&Ksm[krow*64 + (((kh*4 + fg) ^ (krow & 7)) * 8)];
        sacc[0][n] = MFMA16(qf[0][kh], kf, sacc[0][n]);
        sacc[1][n] = MFMA16(qf[1][kh], kf, sacc[1][n]);
      }
    }

    #pragma unroll
    for (int m = 0; m < 2; m++) {
      float pm[4];
      #pragma unroll
      for (int r = 0; r < 4; r++)
        pm[r] = fmaxf(fmaxf(sacc[m][0][r], sacc[m][1][r]),
                      fmaxf(sacc[m][2][r], sacc[m][3][r]));
      #pragma unroll
      for (int msk = 1; msk < 16; msk <<= 1)
        #pragma unroll
        for (int r = 0; r < 4; r++) pm[r] = fmaxf(pm[r], __shfl_xor(pm[r], msk));

      int grow = 0;
      #pragma unroll
      for (int r = 0; r < 4; r++) grow |= (pm[r] > mrow[m][r] + 8.f) ? 1 : 0;
      if (__any(grow)) {
        #pragma unroll
        for (int r = 0; r < 4; r++) {
          const float mn = fmaxf(mrow[m][r], pm[r]);
          const float corr = __expf(mrow[m][r] - mn);
          mrow[m][r] = mn;
          lrow[m][r] *= corr;
          #pragma unroll
          for (int d16 = 0; d16 < 4; d16++) oacc[m][d16][r] *= corr;
        }
      }

      float psum[4] = {0.f, 0.f, 0.f, 0.f};
      #pragma unroll
      for (int n = 0; n < 4; n++)
        #pragma unroll
        for (int r = 0; r < 4; r++) {
          float p = __expf(sacc[m][n][r] - mrow[m][r]);
          sacc[m][n][r] = p;
          psum[r] += p;
        }
      #pragma unroll
      for (int msk = 1; msk < 16; msk <<= 1)
        #pragma unroll
        for (int r = 0; r < 4; r++) psum[r] += __shfl_xor(psum[r], msk);
      #pragma unroll
      for (int r = 0; r < 4; r++) lrow[m][r] += psum[r];
      #pragma unroll
      for (int n = 0; n < 4; n++)
        #pragma unroll
        for (int r = 0; r < 4; r++)
          plds[wid][m*16 + fg*4 + r][n*16 + fr] = f2bf_rn(sacc[m][n][r]);
    }

    short8 pf[2][2];
    #pragma unroll
    for (int m = 0; m < 2; m++)
      #pragma unroll
      for (int kh = 0; kh < 2; kh++)
        pf[m][kh] = *(const short8*)&plds[wid][m*16 + fr][kh*32 + fg*8];

    #pragma unroll
    for (int d16 = 0; d16 < 4; d16++) {
      #pragma unroll
      for (int kh = 0; kh < 2; kh++) {
        const int vrow = d16*16 + fr;
        short8 vf = *(const short8*)&Vsm[vrow*64 + (((kh*4 + fg) ^ (vrow & 7)) * 8)];
        oacc[0][d16] = MFMA16(pf[0][kh], vf, oacc[0][d16]);
        oacc[1][d16] = MFMA16(pf[1][kh], vf, oacc[1][d16]);
      }
    }

    if (it < 15) {
      __syncthreads();
      asm volatile("s_waitcnt vmcnt(0)" ::: "memory");
      *kDst = kr2; *vDst = vr2;
      __syncthreads();
    }
  }

  #pragma unroll
  for (int m = 0; m < 2; m++) {
    float inv[4];
    #pragma unroll
    for (int r = 0; r < 4; r++) inv[r] = 1.0f / lrow[m][r];
    #pragma unroll
    for (int d16 = 0; d16 < 4; d16++) {
      #pragma unroll
      for (int r = 0; r < 4; r++) {
        const int qrow = q0 + m*16 + fg*4 + r;
        const int col = h*64 + d16*16 + fr;
        out[(size_t)(b * 1024 + qrow) * 1024 + col] = f2bf(oacc[m][d16][r] * inv[r]);
      }
    }
  }
}

// ---------------- host launch ----------------
extern "C" void kernel_launch(void* const* d_in, const int* in_sizes, int n_in,
                              void* d_out, int out_size, void* d_ws, size_t ws_size,
                              hipStream_t stream) {
  const float* x      = (const float*)d_in[0];
  const float* ln1_g  = (const float*)d_in[1];
  const float* ln1_b  = (const float*)d_in[2];
  const float* qkv_w  = (const float*)d_in[3];
  const float* qkv_b  = (const float*)d_in[4];
  const float* proj_w = (const float*)d_in[5];
  const float* proj_b = (const float*)d_in[6];
  const float* ls1_g  = (const float*)d_in[7];
  const float* ln2_g  = (const float*)d_in[8];
  const float* ln2_b  = (const float*)d_in[9];
  const float* fc1_w  = (const float*)d_in[10];
  const float* fc1_b  = (const float*)d_in[11];
  const float* fc2_w  = (const float*)d_in[12];
  const float* fc2_b  = (const float*)d_in[13];
  const float* ls2_g  = (const float*)d_in[14];

  char* w = (char*)d_ws;
  unsigned short* wqkvT  = (unsigned short*)(w + 0);           //  6,291,456
  unsigned short* wprojT = (unsigned short*)(w + 6291456);     //  2,097,152
  unsigned short* wfc1T  = (unsigned short*)(w + 8388608);     //  8,388,608
  unsigned short* wfc2T  = (unsigned short*)(w + 16777216);    //  8,388,608
  unsigned short* x1     = (unsigned short*)(w + 25165824);    // 33,554,432 (bf16)
  unsigned short* h1     = (unsigned short*)(w + 58720256);    // 33,554,432
  unsigned short* qkbuf  = (unsigned short*)(w + 92274688);    // 67,108,864 [16384][2048]
  unsigned short* vtbuf  = (unsigned short*)(w + 159383552);   // 33,554,432 [256][64][1024]
  unsigned short* attno  = (unsigned short*)(w + 192937984);   // 33,554,432
  unsigned short* h3     = (unsigned short*)(w + 92274688);    // 134,217,728 (overlay)

  dim3 tb32(32, 8);
  k_transpose_cast<<<dim3(3072/32, 1024/32), tb32, 0, stream>>>(qkv_w,  wqkvT, 1024, 3072);
  k_transpose_cast<<<dim3(1024/32, 1024/32), tb32, 0, stream>>>(proj_w, wprojT, 1024, 1024);
  k_transpose_cast<<<dim3(4096/32, 1024/32), tb32, 0, stream>>>(fc1_w,  wfc1T, 1024, 4096);
  k_transpose_cast<<<dim3(1024/32, 4096/32), tb32, 0, stream>>>(fc2_w,  wfc2T, 4096, 1024);

  // LN1 (f32 in)
  k_layernorm<0><<<16384, 256, 0, stream>>>(x, ln1_g, ln1_b, h1);
  // QKV = h1 @ qkv_w + qkv_b ; Q,K -> qkbuf, V -> vtbuf transposed
  k_gemm128<0><<<128*24, 256, 0, stream>>>(h1, wqkvT, qkv_b, nullptr, nullptr,
                                           qkbuf, vtbuf, 16384, 3072, 1024, 24);
  // attention (XCD-grouped bh mapping)
  k_attn<<<1024, 512, 0, stream>>>(qkbuf, vtbuf, attno);
  // x1(bf16) = x(f32) + (attn @ proj_w + proj_b) * ls1_g
  k_gemm128<2><<<128*8, 256, 0, stream>>>(attno, wprojT, proj_b, x, ls1_g,
                                          x1, nullptr, 16384, 1024, 1024, 8);
  // LN2 (bf16 in)
  k_layernorm<1><<<16384, 256, 0, stream>>>(x1, ln2_g, ln2_b, h1);
  // h3 = gelu(h2 @ fc1_w + fc1_b)
  k_gemm128<1><<<128*32, 256, 0, stream>>>(h1, wfc1T, fc1_b, nullptr, nullptr,
                                           h3, nullptr, 16384, 4096, 1024, 32);
  // out(f32) = x1(bf16) + (h3 @ fc2_w + fc2_b) * ls2_g
  k_gemm128<3><<<128*8, 256, 0, stream>>>(h3, wfc2T, fc2_b, x1, ls2_g,
                                          (float*)d_out, nullptr, 16384, 1024, 4096, 8);
}

// Round 15
// 790.601 us; speedup vs baseline: 1.8906x; 1.0297x over previous
//
#include <hip/hip_runtime.h>
#include <hip/hip_bf16.h>
#include <math.h>

typedef __attribute__((ext_vector_type(8))) short short8;
typedef __attribute__((ext_vector_type(4))) float f32x4;

#define MFMA16(a,b,c) __builtin_amdgcn_mfma_f32_16x16x32_bf16((a),(b),(c),0,0,0)

__device__ __forceinline__ unsigned short f2bf(float f){
  unsigned int u = __builtin_bit_cast(unsigned int, f);
  u += 0x7fffu + ((u >> 16) & 1u);
  return (unsigned short)(u >> 16);
}
__device__ __forceinline__ unsigned short f2bf_rn(float f){
  unsigned int u = __builtin_bit_cast(unsigned int, f);
  return (unsigned short)((u + 0x8000u) >> 16);
}
__device__ __forceinline__ float bf2f(unsigned short u){
  unsigned int v = ((unsigned int)u) << 16;
  return __builtin_bit_cast(float, v);
}

__device__ __forceinline__ void gload16(const void* g, void* lds){
  __builtin_amdgcn_global_load_lds(
      (const __attribute__((address_space(1))) unsigned int*)g,
      (__attribute__((address_space(3))) unsigned int*)lds, 16, 0, 0);
}

// ---------------- weight transpose + cast: in [K][N] f32 -> out [N][K] bf16 ----------------
__global__ __launch_bounds__(256) void k_transpose_cast(const float* __restrict__ in,
    unsigned short* __restrict__ out, int K, int N)
{
  __shared__ unsigned short tile[32][33];
  const int tx = threadIdx.x, ty = threadIdx.y;
  const int n0 = blockIdx.x * 32, k0 = blockIdx.y * 32;
  #pragma unroll
  for (int i = 0; i < 4; i++) {
    int k = k0 + ty + i*8;
    tile[ty + i*8][tx] = f2bf(in[(size_t)k * N + n0 + tx]);
  }
  __syncthreads();
  #pragma unroll
  for (int i = 0; i < 4; i++) {
    int n = n0 + ty + i*8;
    out[(size_t)n * K + k0 + tx] = tile[tx][ty + i*8];
  }
}

// ---------------- layernorm: x [rows][1024] (f32 or bf16) -> out bf16 ----------------
template<int BF16IN>
__global__ __launch_bounds__(256) void k_layernorm(const void* __restrict__ xin,
    const float* __restrict__ g, const float* __restrict__ b,
    unsigned short* __restrict__ out)
{
  const int row = blockIdx.x;
  const int t = threadIdx.x;
  float4 v;
  if (BF16IN) {
    const ushort4 u = ((const ushort4*)((const unsigned short*)xin + (size_t)row * 1024))[t];
    v.x = bf2f(u.x); v.y = bf2f(u.y); v.z = bf2f(u.z); v.w = bf2f(u.w);
  } else {
    v = ((const float4*)((const float*)xin + (size_t)row * 1024))[t];
  }
  float s  = v.x + v.y + v.z + v.w;
  float s2 = v.x*v.x + v.y*v.y + v.z*v.z + v.w*v.w;
  #pragma unroll
  for (int m = 1; m < 64; m <<= 1) {
    s  += __shfl_xor(s,  m);
    s2 += __shfl_xor(s2, m);
  }
  __shared__ float red[2][4];
  const int wid = t >> 6, lane = t & 63;
  if (lane == 0) { red[0][wid] = s; red[1][wid] = s2; }
  __syncthreads();
  s  = red[0][0] + red[0][1] + red[0][2] + red[0][3];
  s2 = red[1][0] + red[1][1] + red[1][2] + red[1][3];
  const float mu = s * (1.0f / 1024.0f);
  const float var = s2 * (1.0f / 1024.0f) - mu * mu;
  const float rstd = rsqrtf(var + 1e-6f);
  const float4 gv = ((const float4*)g)[t];
  const float4 bv = ((const float4*)b)[t];
  ushort4 o;
  o.x = f2bf((v.x - mu) * rstd * gv.x + bv.x);
  o.y = f2bf((v.y - mu) * rstd * gv.y + bv.y);
  o.z = f2bf((v.z - mu) * rstd * gv.z + bv.z);
  o.w = f2bf((v.w - mu) * rstd * gv.w + bv.w);
  ((ushort4*)(out + (size_t)row * 1024))[t] = o;
}

// ---------------- 128x128 MFMA GEMM — m97 structure, BK=64, conflict-free swizzle ----------
// C[M][N] = A[M][K](bf16) * Bt[N][K]^T(bf16) + epilogue
// EPI 0: QKV: bn<16 -> qk (stride 2048) bf16; bn>=16 -> vT[b][h][d][n] bf16
// EPI 1: out bf16 = gelu(acc + bias)
// EPI 2: out bf16 = resid(f32) + (acc+bias)*lsg      (proj -> x1 bf16)
// EPI 3: out f32  = resid(bf16) + (acc+bias)*lsg     (fc2 -> d_out f32)
// launch_bounds(256,3): 3 blocks/CU. (256,4) caps VGPR at 64 -> spill (r12).
template<int EPI>
__global__ __launch_bounds__(256, 3) void k_gemm128(
    const unsigned short* __restrict__ A,
    const unsigned short* __restrict__ Bt,
    const float* __restrict__ bias,
    const void* __restrict__ resid,
    const float* __restrict__ lsg,
    void* __restrict__ outp,
    unsigned short* __restrict__ vtp,
    int M, int N, int K, int nbn)
{
  __shared__ __align__(16) unsigned short Asm[128 * 64];   // 16 KB
  __shared__ __align__(16) unsigned short Bsm[128 * 64];   // 16 KB

  const int bid = blockIdx.x;
  const int mrows = (gridDim.x >> 3) / nbn;
  const int xcd = bid & 7, l = bid >> 3;
  const int bm = xcd * mrows + (l % mrows);
  const int bn = l / mrows;

  const int t = threadIdx.x, lane = t & 63;
  const int wid = t >> 6, wm = wid >> 1, wn = wid & 1;
  const int fr = lane & 15, fg = lane >> 4;

  size_t aOf[4], bOf[4];
  int dOf[4];
  #pragma unroll
  for (int i = 0; i < 4; i++) {
    const int s = i * 256 + t;
    const int row = s >> 3, c = s & 7;
    const int cs = c ^ (row & 7);
    dOf[i] = s * 16;
    aOf[i] = ((size_t)bm * 128 + row) * K + cs * 8;
    bOf[i] = ((size_t)bn * 128 + row) * K + cs * 8;
  }

  f32x4 acc[4][4] = {};

  for (int kt = 0; kt < K; kt += 64) {
    __syncthreads();
    #pragma unroll
    for (int i = 0; i < 4; i++) gload16(A  + aOf[i] + kt, (char*)Asm + dOf[i]);
    #pragma unroll
    for (int i = 0; i < 4; i++) gload16(Bt + bOf[i] + kt, (char*)Bsm + dOf[i]);
    __syncthreads();

    short8 af[4][2], bfv[4][2];
    #pragma unroll
    for (int m = 0; m < 4; m++) {
      const int row = wm * 64 + m * 16 + fr;
      const char* p = (const char*)Asm + row * 128;
      af[m][0] = *(const short8*)(p + ((fg       ^ (row & 7)) * 16));
      af[m][1] = *(const short8*)(p + (((4 + fg) ^ (row & 7)) * 16));
    }
    #pragma unroll
    for (int n = 0; n < 4; n++) {
      const int row = wn * 64 + n * 16 + fr;
      const char* p = (const char*)Bsm + row * 128;
      bfv[n][0] = *(const short8*)(p + ((fg       ^ (row & 7)) * 16));
      bfv[n][1] = *(const short8*)(p + (((4 + fg) ^ (row & 7)) * 16));
    }
    __builtin_amdgcn_s_setprio(1);
    #pragma unroll
    for (int kk = 0; kk < 2; kk++)
      #pragma unroll
      for (int m = 0; m < 4; m++)
        #pragma unroll
        for (int n = 0; n < 4; n++)
          acc[m][n] = MFMA16(af[m][kk], bfv[n][kk], acc[m][n]);
    __builtin_amdgcn_s_setprio(0);
  }

  const int row0 = bm * 128 + wm * 64 + fg * 4;
  const int col0 = bn * 128 + wn * 64 + fr;
  #pragma unroll
  for (int n = 0; n < 4; n++) {
    const int col = col0 + n * 16;
    const float bcol = bias[col];
    float lscale = 0.f;
    if (EPI >= 2) lscale = lsg[col];
    #pragma unroll
    for (int m = 0; m < 4; m++) {
      #pragma unroll
      for (int r = 0; r < 4; r++) {
        const int row = row0 + m * 16 + r;
        float v = acc[m][n][r] + bcol;
        if (EPI == 0) {
          if (bn < 16) {
            ((unsigned short*)outp)[(size_t)row * 2048 + col] = f2bf(v);
          } else {
            const int d = col - 2048, hh = d >> 6, dd = d & 63;
            const int bb = row >> 10, nn = row & 1023;
            vtp[(((size_t)bb * 16 + hh) * 64 + dd) * 1024 + nn] = f2bf(v);
          }
        } else if (EPI == 1) {
          const float u = v * (0.7978845608f + 0.0356774081f * v * v);
          v = v * __builtin_amdgcn_rcpf(1.0f + __expf(-2.0f * u));
          ((unsigned short*)outp)[(size_t)row * N + col] = f2bf(v);
        } else if (EPI == 2) {
          const float rv = ((const float*)resid)[(size_t)row * N + col];
          ((unsigned short*)outp)[(size_t)row * N + col] = f2bf(rv + v * lscale);
        } else {
          const float rv = bf2f(((const unsigned short*)resid)[(size_t)row * N + col]);
          ((float*)outp)[(size_t)row * N + col] = rv + v * lscale;
        }
      }
    }
  }
}

// ---------------- flash attention (no 1/sqrt(d) scale, faithful to ref) ----------------
// qk: [16384][2048] bf16 ; vT: [b][h][64 d][1024 n] bf16 ; out: [16384][1024] bf16
// K/V double-buffered via global_load_lds (zero VGPR cost): prefetch tile t+1
// issued BEFORE tile t's compute; the single end-of-iter __syncthreads (implicit
// vmcnt0+lgkm drain) lands AFTER compute -> stage latency hidden.
// P round-trip: 16-row per-wave buffer, m-sequential (write rows, read frags,
// reuse for m=1 — DS ops are in-order per wave, WAR safe). r14 lesson: P needs
// >= 64 columns (pad 72); the 40-col buffer was an overflow.
__global__ __launch_bounds__(512) void k_attn(const unsigned short* __restrict__ qk,
                                              const unsigned short* __restrict__ vT,
                                              unsigned short* __restrict__ out)
{
  const int bid = blockIdx.x;
  const int xcd = bid & 7, l = bid >> 3;
  const int bh = xcd * 32 + (l >> 2);
  const int qt = l & 3;
  const int b = bh >> 4, h = bh & 15;
  const int t = threadIdx.x, lane = t & 63, wid = t >> 6;
  const int fr = lane & 15, fg = lane >> 4;
  const int q0 = qt * 256 + wid * 32;

  __shared__ __align__(16) unsigned short Ksm[2][64 * 64];   // 2 x 8 KB
  __shared__ __align__(16) unsigned short Vsm[2][64 * 64];   // 2 x 8 KB
  __shared__ __align__(16) unsigned short plds[8][16][72];   // 18 KB (total 50 KB -> 3 blocks/CU)

  const size_t qbase = (size_t)b * 1024 * 2048 + (size_t)h * 64;
  const size_t kbase = qbase + 1024;
  const size_t vbase = (size_t)bh * 64 * 1024;

  short8 qf[2][2];
  #pragma unroll
  for (int m = 0; m < 2; m++)
    #pragma unroll
    for (int kh = 0; kh < 2; kh++)
      qf[m][kh] = *(const short8*)(qk + qbase + (size_t)(q0 + m*16 + fr) * 2048
                                   + kh*32 + fg*8);

  f32x4 oacc[2][4] = {};
  float mrow[2][4], lrow[2][4];
  #pragma unroll
  for (int m = 0; m < 2; m++)
    #pragma unroll
    for (int r = 0; r < 4; r++) { mrow[m][r] = -1e30f; lrow[m][r] = 0.f; }

  const int srow = t >> 3, sc = t & 7;
  const int scs = sc ^ (srow & 7);
  const unsigned short* kSrc = qk + kbase + (size_t)srow * 2048 + scs*8;
  const unsigned short* vSrc = vT + vbase + (size_t)srow * 1024 + scs*8;

  // prologue: stage tile 0 into buf 0
  gload16(kSrc, (char*)&Ksm[0][0] + t*16);
  gload16(vSrc, (char*)&Vsm[0][0] + t*16);
  __syncthreads();

  for (int it = 0; it < 16; ++it) {
    const int buf = it & 1;
    // prefetch tile it+1 into buf^1 (latency hidden under this iter's compute)
    if (it < 15) {
      gload16(kSrc + (size_t)(it + 1) * 64 * 2048, (char*)&Ksm[buf ^ 1][0] + t*16);
      gload16(vSrc + (it + 1) * 64,                (char*)&Vsm[buf ^ 1][0] + t*16);
    }

    // ---- S = Q K^T from Ksm[buf] ----
    f32x4 sacc[2][4] = {};
    #pragma unroll
    for (int n = 0; n < 4; n++) {
      #pragma unroll
      for (int kh = 0; kh < 2; kh++) {
        const int krow = n*16 + fr;
        short8 kf = *(const short8*)&Ksm[buf][krow*64 + (((kh*4 + fg) ^ (krow & 7)) * 8)];
        sacc[0][n] = MFMA16(qf[0][kh], kf, sacc[0][n]);
        sacc[1][n] = MFMA16(qf[1][kh], kf, sacc[1][n]);
      }
    }

    // ---- online softmax + P->bf16 frags (m-sequential through 16-row plds) ----
    short8 pf[2][2];
    #pragma unroll
    for (int m = 0; m < 2; m++) {
      float pm[4];
      #pragma unroll
      for (int r = 0; r < 4; r++)
        pm[r] = fmaxf(fmaxf(sacc[m][0][r], sacc[m][1][r]),
                      fmaxf(sacc[m][2][r], sacc[m][3][r]));
      #pragma unroll
      for (int msk = 1; msk < 16; msk <<= 1)
        #pragma unroll
        for (int r = 0; r < 4; r++) pm[r] = fmaxf(pm[r], __shfl_xor(pm[r], msk));

      int grow = 0;
      #pragma unroll
      for (int r = 0; r < 4; r++) grow |= (pm[r] > mrow[m][r] + 8.f) ? 1 : 0;
      if (__any(grow)) {
        #pragma unroll
        for (int r = 0; r < 4; r++) {
          const float mn = fmaxf(mrow[m][r], pm[r]);
          const float corr = __expf(mrow[m][r] - mn);
          mrow[m][r] = mn;
          lrow[m][r] *= corr;
          #pragma unroll
          for (int d16 = 0; d16 < 4; d16++) oacc[m][d16][r] *= corr;
        }
      }

      float psum[4] = {0.f, 0.f, 0.f, 0.f};
      #pragma unroll
      for (int n = 0; n < 4; n++)
        #pragma unroll
        for (int r = 0; r < 4; r++) {
          float p = __expf(sacc[m][n][r] - mrow[m][r]);
          sacc[m][n][r] = p;
          psum[r] += p;
        }
      #pragma unroll
      for (int msk = 1; msk < 16; msk <<= 1)
        #pragma unroll
        for (int r = 0; r < 4; r++) psum[r] += __shfl_xor(psum[r], msk);
      #pragma unroll
      for (int r = 0; r < 4; r++) lrow[m][r] += psum[r];

      // write this m's 16 P rows, then read its A-fragments (WAR-safe: DS in-order)
      #pragma unroll
      for (int n = 0; n < 4; n++)
        #pragma unroll
        for (int r = 0; r < 4; r++)
          plds[wid][fg*4 + r][n*16 + fr] = f2bf_rn(sacc[m][n][r]);
      #pragma unroll
      for (int kh = 0; kh < 2; kh++)
        pf[m][kh] = *(const short8*)&plds[wid][fr][kh*32 + fg*8];
    }

    // ---- O += P V from Vsm[buf] ----
    #pragma unroll
    for (int d16 = 0; d16 < 4; d16++) {
      #pragma unroll
      for (int kh = 0; kh < 2; kh++) {
        const int vrow = d16*16 + fr;
        short8 vf = *(const short8*)&Vsm[buf][vrow*64 + (((kh*4 + fg) ^ (vrow & 7)) * 8)];
        oacc[0][d16] = MFMA16(pf[0][kh], vf, oacc[0][d16]);
        oacc[1][d16] = MFMA16(pf[1][kh], vf, oacc[1][d16]);
      }
    }

    // one barrier/iter: drains prefetch (vmcnt) + retires all reads of buf
    __syncthreads();
  }

  #pragma unroll
  for (int m = 0; m < 2; m++) {
    float inv[4];
    #pragma unroll
    for (int r = 0; r < 4; r++) inv[r] = 1.0f / lrow[m][r];
    #pragma unroll
    for (int d16 = 0; d16 < 4; d16++) {
      #pragma unroll
      for (int r = 0; r < 4; r++) {
        const int qrow = q0 + m*16 + fg*4 + r;
        const int col = h*64 + d16*16 + fr;
        out[(size_t)(b * 1024 + qrow) * 1024 + col] = f2bf(oacc[m][d16][r] * inv[r]);
      }
    }
  }
}

// ---------------- host launch ----------------
extern "C" void kernel_launch(void* const* d_in, const int* in_sizes, int n_in,
                              void* d_out, int out_size, void* d_ws, size_t ws_size,
                              hipStream_t stream) {
  const float* x      = (const float*)d_in[0];
  const float* ln1_g  = (const float*)d_in[1];
  const float* ln1_b  = (const float*)d_in[2];
  const float* qkv_w  = (const float*)d_in[3];
  const float* qkv_b  = (const float*)d_in[4];
  const float* proj_w = (const float*)d_in[5];
  const float* proj_b = (const float*)d_in[6];
  const float* ls1_g  = (const float*)d_in[7];
  const float* ln2_g  = (const float*)d_in[8];
  const float* ln2_b  = (const float*)d_in[9];
  const float* fc1_w  = (const float*)d_in[10];
  const float* fc1_b  = (const float*)d_in[11];
  const float* fc2_w  = (const float*)d_in[12];
  const float* fc2_b  = (const float*)d_in[13];
  const float* ls2_g  = (const float*)d_in[14];

  char* w = (char*)d_ws;
  unsigned short* wqkvT  = (unsigned short*)(w + 0);           //  6,291,456
  unsigned short* wprojT = (unsigned short*)(w + 6291456);     //  2,097,152
  unsigned short* wfc1T  = (unsigned short*)(w + 8388608);     //  8,388,608
  unsigned short* wfc2T  = (unsigned short*)(w + 16777216);    //  8,388,608
  unsigned short* x1     = (unsigned short*)(w + 25165824);    // 33,554,432 (bf16)
  unsigned short* h1     = (unsigned short*)(w + 58720256);    // 33,554,432
  unsigned short* qkbuf  = (unsigned short*)(w + 92274688);    // 67,108,864 [16384][2048]
  unsigned short* vtbuf  = (unsigned short*)(w + 159383552);   // 33,554,432 [256][64][1024]
  unsigned short* attno  = (unsigned short*)(w + 192937984);   // 33,554,432
  unsigned short* h3     = (unsigned short*)(w + 92274688);    // 134,217,728 (overlay)

  dim3 tb32(32, 8);
  k_transpose_cast<<<dim3(3072/32, 1024/32), tb32, 0, stream>>>(qkv_w,  wqkvT, 1024, 3072);
  k_transpose_cast<<<dim3(1024/32, 1024/32), tb32, 0, stream>>>(proj_w, wprojT, 1024, 1024);
  k_transpose_cast<<<dim3(4096/32, 1024/32), tb32, 0, stream>>>(fc1_w,  wfc1T, 1024, 4096);
  k_transpose_cast<<<dim3(1024/32, 4096/32), tb32, 0, stream>>>(fc2_w,  wfc2T, 4096, 1024);

  // LN1 (f32 in)
  k_layernorm<0><<<16384, 256, 0, stream>>>(x, ln1_g, ln1_b, h1);
  // QKV = h1 @ qkv_w + qkv_b ; Q,K -> qkbuf, V -> vtbuf transposed
  k_gemm128<0><<<128*24, 256, 0, stream>>>(h1, wqkvT, qkv_b, nullptr, nullptr,
                                           qkbuf, vtbuf, 16384, 3072, 1024, 24);
  // attention (XCD-grouped bh mapping)
  k_attn<<<1024, 512, 0, stream>>>(qkbuf, vtbuf, attno);
  // x1(bf16) = x(f32) + (attn @ proj_w + proj_b) * ls1_g
  k_gemm128<2><<<128*8, 256, 0, stream>>>(attno, wprojT, proj_b, x, ls1_g,
                                          x1, nullptr, 16384, 1024, 1024, 8);
  // LN2 (bf16 in)
  k_layernorm<1><<<16384, 256, 0, stream>>>(x1, ln2_g, ln2_b, h1);
  // h3 = gelu(h2 @ fc1_w + fc1_b)
  k_gemm128<1><<<128*32, 256, 0, stream>>>(h1, wfc1T, fc1_b, nullptr, nullptr,
                                           h3, nullptr, 16384, 4096, 1024, 32);
  // out(f32) = x1(bf16) + (h3 @ fc2_w + fc2_b) * ls2_g
  k_gemm128<3><<<128*8, 256, 0, stream>>>(h3, wfc2T, fc2_b, x1, ls2_g,
                                          (float*)d_out, nullptr, 16384, 1024, 4096, 8);
}

// Round 16
// 784.883 us; speedup vs baseline: 1.9044x; 1.0073x over previous
//
#include <hip/hip_runtime.h>
#include <hip/hip_bf16.h>
#include <math.h>

typedef __attribute__((ext_vector_type(8))) short short8;
typedef __attribute__((ext_vector_type(4))) float f32x4;

#define MFMA16(a,b,c) __builtin_amdgcn_mfma_f32_16x16x32_bf16((a),(b),(c),0,0,0)

__device__ __forceinline__ unsigned short f2bf(float f){
  unsigned int u = __builtin_bit_cast(unsigned int, f);
  u += 0x7fffu + ((u >> 16) & 1u);
  return (unsigned short)(u >> 16);
}
__device__ __forceinline__ unsigned short f2bf_rn(float f){
  unsigned int u = __builtin_bit_cast(unsigned int, f);
  return (unsigned short)((u + 0x8000u) >> 16);
}
__device__ __forceinline__ float bf2f(unsigned short u){
  unsigned int v = ((unsigned int)u) << 16;
  return __builtin_bit_cast(float, v);
}

__device__ __forceinline__ void gload16(const void* g, void* lds){
  __builtin_amdgcn_global_load_lds(
      (const __attribute__((address_space(1))) unsigned int*)g,
      (__attribute__((address_space(3))) unsigned int*)lds, 16, 0, 0);
}

// ---------------- weight transpose + cast: in [K][N] f32 -> out [N][K] bf16 ----------------
__global__ __launch_bounds__(256) void k_transpose_cast(const float* __restrict__ in,
    unsigned short* __restrict__ out, int K, int N)
{
  __shared__ unsigned short tile[32][33];
  const int tx = threadIdx.x, ty = threadIdx.y;
  const int n0 = blockIdx.x * 32, k0 = blockIdx.y * 32;
  #pragma unroll
  for (int i = 0; i < 4; i++) {
    int k = k0 + ty + i*8;
    tile[ty + i*8][tx] = f2bf(in[(size_t)k * N + n0 + tx]);
  }
  __syncthreads();
  #pragma unroll
  for (int i = 0; i < 4; i++) {
    int n = n0 + ty + i*8;
    out[(size_t)n * K + k0 + tx] = tile[tx][ty + i*8];
  }
}

// ---------------- layernorm: x [rows][1024] (f32 or bf16) -> out bf16 ----------------
template<int BF16IN>
__global__ __launch_bounds__(256) void k_layernorm(const void* __restrict__ xin,
    const float* __restrict__ g, const float* __restrict__ b,
    unsigned short* __restrict__ out)
{
  const int row = blockIdx.x;
  const int t = threadIdx.x;
  float4 v;
  if (BF16IN) {
    const ushort4 u = ((const ushort4*)((const unsigned short*)xin + (size_t)row * 1024))[t];
    v.x = bf2f(u.x); v.y = bf2f(u.y); v.z = bf2f(u.z); v.w = bf2f(u.w);
  } else {
    v = ((const float4*)((const float*)xin + (size_t)row * 1024))[t];
  }
  float s  = v.x + v.y + v.z + v.w;
  float s2 = v.x*v.x + v.y*v.y + v.z*v.z + v.w*v.w;
  #pragma unroll
  for (int m = 1; m < 64; m <<= 1) {
    s  += __shfl_xor(s,  m);
    s2 += __shfl_xor(s2, m);
  }
  __shared__ float red[2][4];
  const int wid = t >> 6, lane = t & 63;
  if (lane == 0) { red[0][wid] = s; red[1][wid] = s2; }
  __syncthreads();
  s  = red[0][0] + red[0][1] + red[0][2] + red[0][3];
  s2 = red[1][0] + red[1][1] + red[1][2] + red[1][3];
  const float mu = s * (1.0f / 1024.0f);
  const float var = s2 * (1.0f / 1024.0f) - mu * mu;
  const float rstd = rsqrtf(var + 1e-6f);
  const float4 gv = ((const float4*)g)[t];
  const float4 bv = ((const float4*)b)[t];
  ushort4 o;
  o.x = f2bf((v.x - mu) * rstd * gv.x + bv.x);
  o.y = f2bf((v.y - mu) * rstd * gv.y + bv.y);
  o.z = f2bf((v.z - mu) * rstd * gv.z + bv.z);
  o.w = f2bf((v.w - mu) * rstd * gv.w + bv.w);
  ((ushort4*)(out + (size_t)row * 1024))[t] = o;
}

// ---------------- 128x128 MFMA GEMM — m97 structure, BK=64, 4 blocks/CU ----------
// C[M][N] = A[M][K](bf16) * Bt[N][K]^T(bf16) + epilogue
// EPI 0: QKV: bn<16 -> qk (stride 2048) bf16; bn>=16 -> vT[b][h][d][n] bf16
// EPI 1: out bf16 = gelu(acc + bias)
// EPI 2: out bf16 = resid(f32) + (acc+bias)*lsg      (proj -> x1 bf16)
// EPI 3: out f32  = resid(bf16) + (acc+bias)*lsg     (fc2 -> d_out f32)
//
// r16: kk-loop split so only ONE kk's fragments are live (32 VGPR not 64) ->
// unified regs ~124 < 128 -> 4 waves/SIMD (m69 step), 4 blocks/CU, 16 waves/CU.
// All grids (1024/1536.../4096) are exact multiples of the 1024 slots -> no
// residency-wave tail. r12's (256,4) failed because the UNSPLIT code needed
// 144 regs -> forced spill; this version genuinely fits.
template<int EPI>
__global__ __launch_bounds__(256, 4) void k_gemm128(
    const unsigned short* __restrict__ A,
    const unsigned short* __restrict__ Bt,
    const float* __restrict__ bias,
    const void* __restrict__ resid,
    const float* __restrict__ lsg,
    void* __restrict__ outp,
    unsigned short* __restrict__ vtp,
    int M, int N, int K, int nbn)
{
  __shared__ __align__(16) unsigned short Asm[128 * 64];   // 16 KB
  __shared__ __align__(16) unsigned short Bsm[128 * 64];   // 16 KB

  const int bid = blockIdx.x;
  const int mrows = (gridDim.x >> 3) / nbn;
  const int xcd = bid & 7, l = bid >> 3;
  const int bm = xcd * mrows + (l % mrows);
  const int bn = l / mrows;

  const int t = threadIdx.x, lane = t & 63;
  const int wid = t >> 6, wm = wid >> 1, wn = wid & 1;
  const int fr = lane & 15, fg = lane >> 4;

  size_t aOf[4], bOf[4];
  int dOf[4];
  #pragma unroll
  for (int i = 0; i < 4; i++) {
    const int s = i * 256 + t;
    const int row = s >> 3, c = s & 7;
    const int cs = c ^ (row & 7);
    dOf[i] = s * 16;
    aOf[i] = ((size_t)bm * 128 + row) * K + cs * 8;
    bOf[i] = ((size_t)bn * 128 + row) * K + cs * 8;
  }

  f32x4 acc[4][4] = {};

  for (int kt = 0; kt < K; kt += 64) {
    __syncthreads();
    #pragma unroll
    for (int i = 0; i < 4; i++) gload16(A  + aOf[i] + kt, (char*)Asm + dOf[i]);
    #pragma unroll
    for (int i = 0; i < 4; i++) gload16(Bt + bOf[i] + kt, (char*)Bsm + dOf[i]);
    __syncthreads();

    #pragma unroll
    for (int kk = 0; kk < 2; kk++) {
      short8 af[4], bfv[4];
      #pragma unroll
      for (int m = 0; m < 4; m++) {
        const int row = wm * 64 + m * 16 + fr;
        af[m] = *(const short8*)((const char*)Asm + row * 128
                                 + (((kk*4 + fg) ^ (row & 7)) * 16));
      }
      #pragma unroll
      for (int n = 0; n < 4; n++) {
        const int row = wn * 64 + n * 16 + fr;
        bfv[n] = *(const short8*)((const char*)Bsm + row * 128
                                  + (((kk*4 + fg) ^ (row & 7)) * 16));
      }
      __builtin_amdgcn_s_setprio(1);
      #pragma unroll
      for (int m = 0; m < 4; m++)
        #pragma unroll
        for (int n = 0; n < 4; n++)
          acc[m][n] = MFMA16(af[m], bfv[n], acc[m][n]);
      __builtin_amdgcn_s_setprio(0);
    }
  }

  const int row0 = bm * 128 + wm * 64 + fg * 4;
  const int col0 = bn * 128 + wn * 64 + fr;
  #pragma unroll
  for (int n = 0; n < 4; n++) {
    const int col = col0 + n * 16;
    const float bcol = bias[col];
    float lscale = 0.f;
    if (EPI >= 2) lscale = lsg[col];
    #pragma unroll
    for (int m = 0; m < 4; m++) {
      #pragma unroll
      for (int r = 0; r < 4; r++) {
        const int row = row0 + m * 16 + r;
        float v = acc[m][n][r] + bcol;
        if (EPI == 0) {
          if (bn < 16) {
            ((unsigned short*)outp)[(size_t)row * 2048 + col] = f2bf(v);
          } else {
            const int d = col - 2048, hh = d >> 6, dd = d & 63;
            const int bb = row >> 10, nn = row & 1023;
            vtp[(((size_t)bb * 16 + hh) * 64 + dd) * 1024 + nn] = f2bf(v);
          }
        } else if (EPI == 1) {
          const float u = v * (0.7978845608f + 0.0356774081f * v * v);
          v = v * __builtin_amdgcn_rcpf(1.0f + __expf(-2.0f * u));
          ((unsigned short*)outp)[(size_t)row * N + col] = f2bf(v);
        } else if (EPI == 2) {
          const float rv = ((const float*)resid)[(size_t)row * N + col];
          ((unsigned short*)outp)[(size_t)row * N + col] = f2bf(rv + v * lscale);
        } else {
          const float rv = bf2f(((const unsigned short*)resid)[(size_t)row * N + col]);
          ((float*)outp)[(size_t)row * N + col] = rv + v * lscale;
        }
      }
    }
  }
}

// ---------------- flash attention (no 1/sqrt(d) scale, faithful to ref) ----------------
// qk: [16384][2048] bf16 ; vT: [b][h][64 d][1024 n] bf16 ; out: [16384][1024] bf16
// K/V double-buffered via global_load_lds; P round-trip via 16-row per-wave
// buffer, m-sequential (DS in-order, WAR safe). See r15.
__global__ __launch_bounds__(512) void k_attn(const unsigned short* __restrict__ qk,
                                              const unsigned short* __restrict__ vT,
                                              unsigned short* __restrict__ out)
{
  const int bid = blockIdx.x;
  const int xcd = bid & 7, l = bid >> 3;
  const int bh = xcd * 32 + (l >> 2);
  const int qt = l & 3;
  const int b = bh >> 4, h = bh & 15;
  const int t = threadIdx.x, lane = t & 63, wid = t >> 6;
  const int fr = lane & 15, fg = lane >> 4;
  const int q0 = qt * 256 + wid * 32;

  __shared__ __align__(16) unsigned short Ksm[2][64 * 64];   // 2 x 8 KB
  __shared__ __align__(16) unsigned short Vsm[2][64 * 64];   // 2 x 8 KB
  __shared__ __align__(16) unsigned short plds[8][16][72];   // 18 KB (total 50 KB)

  const size_t qbase = (size_t)b * 1024 * 2048 + (size_t)h * 64;
  const size_t kbase = qbase + 1024;
  const size_t vbase = (size_t)bh * 64 * 1024;

  short8 qf[2][2];
  #pragma unroll
  for (int m = 0; m < 2; m++)
    #pragma unroll
    for (int kh = 0; kh < 2; kh++)
      qf[m][kh] = *(const short8*)(qk + qbase + (size_t)(q0 + m*16 + fr) * 2048
                                   + kh*32 + fg*8);

  f32x4 oacc[2][4] = {};
  float mrow[2][4], lrow[2][4];
  #pragma unroll
  for (int m = 0; m < 2; m++)
    #pragma unroll
    for (int r = 0; r < 4; r++) { mrow[m][r] = -1e30f; lrow[m][r] = 0.f; }

  const int srow = t >> 3, sc = t & 7;
  const int scs = sc ^ (srow & 7);
  const unsigned short* kSrc = qk + kbase + (size_t)srow * 2048 + scs*8;
  const unsigned short* vSrc = vT + vbase + (size_t)srow * 1024 + scs*8;

  gload16(kSrc, (char*)&Ksm[0][0] + t*16);
  gload16(vSrc, (char*)&Vsm[0][0] + t*16);
  __syncthreads();

  for (int it = 0; it < 16; ++it) {
    const int buf = it & 1;
    if (it < 15) {
      gload16(kSrc + (size_t)(it + 1) * 64 * 2048, (char*)&Ksm[buf ^ 1][0] + t*16);
      gload16(vSrc + (it + 1) * 64,                (char*)&Vsm[buf ^ 1][0] + t*16);
    }

    f32x4 sacc[2][4] = {};
    #pragma unroll
    for (int n = 0; n < 4; n++) {
      #pragma unroll
      for (int kh = 0; kh < 2; kh++) {
        const int krow = n*16 + fr;
        short8 kf = *(const short8*)&Ksm[buf][krow*64 + (((kh*4 + fg) ^ (krow & 7)) * 8)];
        sacc[0][n] = MFMA16(qf[0][kh], kf, sacc[0][n]);
        sacc[1][n] = MFMA16(qf[1][kh], kf, sacc[1][n]);
      }
    }

    short8 pf[2][2];
    #pragma unroll
    for (int m = 0; m < 2; m++) {
      float pm[4];
      #pragma unroll
      for (int r = 0; r < 4; r++)
        pm[r] = fmaxf(fmaxf(sacc[m][0][r], sacc[m][1][r]),
                      fmaxf(sacc[m][2][r], sacc[m][3][r]));
      #pragma unroll
      for (int msk = 1; msk < 16; msk <<= 1)
        #pragma unroll
        for (int r = 0; r < 4; r++) pm[r] = fmaxf(pm[r], __shfl_xor(pm[r], msk));

      int grow = 0;
      #pragma unroll
      for (int r = 0; r < 4; r++) grow |= (pm[r] > mrow[m][r] + 8.f) ? 1 : 0;
      if (__any(grow)) {
        #pragma unroll
        for (int r = 0; r < 4; r++) {
          const float mn = fmaxf(mrow[m][r], pm[r]);
          const float corr = __expf(mrow[m][r] - mn);
          mrow[m][r] = mn;
          lrow[m][r] *= corr;
          #pragma unroll
          for (int d16 = 0; d16 < 4; d16++) oacc[m][d16][r] *= corr;
        }
      }

      float psum[4] = {0.f, 0.f, 0.f, 0.f};
      #pragma unroll
      for (int n = 0; n < 4; n++)
        #pragma unroll
        for (int r = 0; r < 4; r++) {
          float p = __expf(sacc[m][n][r] - mrow[m][r]);
          sacc[m][n][r] = p;
          psum[r] += p;
        }
      #pragma unroll
      for (int msk = 1; msk < 16; msk <<= 1)
        #pragma unroll
        for (int r = 0; r < 4; r++) psum[r] += __shfl_xor(psum[r], msk);
      #pragma unroll
      for (int r = 0; r < 4; r++) lrow[m][r] += psum[r];

      #pragma unroll
      for (int n = 0; n < 4; n++)
        #pragma unroll
        for (int r = 0; r < 4; r++)
          plds[wid][fg*4 + r][n*16 + fr] = f2bf_rn(sacc[m][n][r]);
      #pragma unroll
      for (int kh = 0; kh < 2; kh++)
        pf[m][kh] = *(const short8*)&plds[wid][fr][kh*32 + fg*8];
    }

    #pragma unroll
    for (int d16 = 0; d16 < 4; d16++) {
      #pragma unroll
      for (int kh = 0; kh < 2; kh++) {
        const int vrow = d16*16 + fr;
        short8 vf = *(const short8*)&Vsm[buf][vrow*64 + (((kh*4 + fg) ^ (vrow & 7)) * 8)];
        oacc[0][d16] = MFMA16(pf[0][kh], vf, oacc[0][d16]);
        oacc[1][d16] = MFMA16(pf[1][kh], vf, oacc[1][d16]);
      }
    }

    __syncthreads();
  }

  #pragma unroll
  for (int m = 0; m < 2; m++) {
    float inv[4];
    #pragma unroll
    for (int r = 0; r < 4; r++) inv[r] = 1.0f / lrow[m][r];
    #pragma unroll
    for (int d16 = 0; d16 < 4; d16++) {
      #pragma unroll
      for (int r = 0; r < 4; r++) {
        const int qrow = q0 + m*16 + fg*4 + r;
        const int col = h*64 + d16*16 + fr;
        out[(size_t)(b * 1024 + qrow) * 1024 + col] = f2bf(oacc[m][d16][r] * inv[r]);
      }
    }
  }
}

// ---------------- host launch ----------------
extern "C" void kernel_launch(void* const* d_in, const int* in_sizes, int n_in,
                              void* d_out, int out_size, void* d_ws, size_t ws_size,
                              hipStream_t stream) {
  const float* x      = (const float*)d_in[0];
  const float* ln1_g  = (const float*)d_in[1];
  const float* ln1_b  = (const float*)d_in[2];
  const float* qkv_w  = (const float*)d_in[3];
  const float* qkv_b  = (const float*)d_in[4];
  const float* proj_w = (const float*)d_in[5];
  const float* proj_b = (const float*)d_in[6];
  const float* ls1_g  = (const float*)d_in[7];
  const float* ln2_g  = (const float*)d_in[8];
  const float* ln2_b  = (const float*)d_in[9];
  const float* fc1_w  = (const float*)d_in[10];
  const float* fc1_b  = (const float*)d_in[11];
  const float* fc2_w  = (const float*)d_in[12];
  const float* fc2_b  = (const float*)d_in[13];
  const float* ls2_g  = (const float*)d_in[14];

  char* w = (char*)d_ws;
  unsigned short* wqkvT  = (unsigned short*)(w + 0);           //  6,291,456
  unsigned short* wprojT = (unsigned short*)(w + 6291456);     //  2,097,152
  unsigned short* wfc1T  = (unsigned short*)(w + 8388608);     //  8,388,608
  unsigned short* wfc2T  = (unsigned short*)(w + 16777216);    //  8,388,608
  unsigned short* x1     = (unsigned short*)(w + 25165824);    // 33,554,432 (bf16)
  unsigned short* h1     = (unsigned short*)(w + 58720256);    // 33,554,432
  unsigned short* qkbuf  = (unsigned short*)(w + 92274688);    // 67,108,864 [16384][2048]
  unsigned short* vtbuf  = (unsigned short*)(w + 159383552);   // 33,554,432 [256][64][1024]
  unsigned short* attno  = (unsigned short*)(w + 192937984);   // 33,554,432
  unsigned short* h3     = (unsigned short*)(w + 92274688);    // 134,217,728 (overlay)

  dim3 tb32(32, 8);
  k_transpose_cast<<<dim3(3072/32, 1024/32), tb32, 0, stream>>>(qkv_w,  wqkvT, 1024, 3072);
  k_transpose_cast<<<dim3(1024/32, 1024/32), tb32, 0, stream>>>(proj_w, wprojT, 1024, 1024);
  k_transpose_cast<<<dim3(4096/32, 1024/32), tb32, 0, stream>>>(fc1_w,  wfc1T, 1024, 4096);
  k_transpose_cast<<<dim3(1024/32, 4096/32), tb32, 0, stream>>>(fc2_w,  wfc2T, 4096, 1024);

  // LN1 (f32 in)
  k_layernorm<0><<<16384, 256, 0, stream>>>(x, ln1_g, ln1_b, h1);
  // QKV = h1 @ qkv_w + qkv_b ; Q,K -> qkbuf, V -> vtbuf transposed
  k_gemm128<0><<<128*24, 256, 0, stream>>>(h1, wqkvT, qkv_b, nullptr, nullptr,
                                           qkbuf, vtbuf, 16384, 3072, 1024, 24);
  // attention (XCD-grouped bh mapping)
  k_attn<<<1024, 512, 0, stream>>>(qkbuf, vtbuf, attno);
  // x1(bf16) = x(f32) + (attn @ proj_w + proj_b) * ls1_g
  k_gemm128<2><<<128*8, 256, 0, stream>>>(attno, wprojT, proj_b, x, ls1_g,
                                          x1, nullptr, 16384, 1024, 1024, 8);
  // LN2 (bf16 in)
  k_layernorm<1><<<16384, 256, 0, stream>>>(x1, ln2_g, ln2_b, h1);
  // h3 = gelu(h2 @ fc1_w + fc1_b)
  k_gemm128<1><<<128*32, 256, 0, stream>>>(h1, wfc1T, fc1_b, nullptr, nullptr,
                                           h3, nullptr, 16384, 4096, 1024, 32);
  // out(f32) = x1(bf16) + (h3 @ fc2_w + fc2_b) * ls2_g
  k_gemm128<3><<<128*8, 256, 0, stream>>>(h3, wfc2T, fc2_b, x1, ls2_g,
                                          (float*)d_out, nullptr, 16384, 1024, 4096, 8);
}

// Round 17
// 767.659 us; speedup vs baseline: 1.9471x; 1.0224x over previous
//
#include <hip/hip_runtime.h>
#include <hip/hip_bf16.h>
#include <math.h>

typedef __attribute__((ext_vector_type(8))) short short8;
typedef __attribute__((ext_vector_type(4))) float f32x4;

#define MFMA16(a,b,c) __builtin_amdgcn_mfma_f32_16x16x32_bf16((a),(b),(c),0,0,0)

__device__ __forceinline__ unsigned short f2bf(float f){
  unsigned int u = __builtin_bit_cast(unsigned int, f);
  u += 0x7fffu + ((u >> 16) & 1u);
  return (unsigned short)(u >> 16);
}
__device__ __forceinline__ unsigned short f2bf_rn(float f){
  unsigned int u = __builtin_bit_cast(unsigned int, f);
  return (unsigned short)((u + 0x8000u) >> 16);
}
__device__ __forceinline__ float bf2f(unsigned short u){
  unsigned int v = ((unsigned int)u) << 16;
  return __builtin_bit_cast(float, v);
}
__device__ __forceinline__ float exp2fast(float x){
  return __builtin_amdgcn_exp2f(x);   // bare v_exp_f32 (input already in log2 domain)
}

__device__ __forceinline__ void gload16(const void* g, void* lds){
  __builtin_amdgcn_global_load_lds(
      (const __attribute__((address_space(1))) unsigned int*)g,
      (__attribute__((address_space(3))) unsigned int*)lds, 16, 0, 0);
}

// ---------------- weight transpose + cast: in [K][N] f32 -> out [N][K] bf16 ----------------
__global__ __launch_bounds__(256) void k_transpose_cast(const float* __restrict__ in,
    unsigned short* __restrict__ out, int K, int N)
{
  __shared__ unsigned short tile[32][33];
  const int tx = threadIdx.x, ty = threadIdx.y;
  const int n0 = blockIdx.x * 32, k0 = blockIdx.y * 32;
  #pragma unroll
  for (int i = 0; i < 4; i++) {
    int k = k0 + ty + i*8;
    tile[ty + i*8][tx] = f2bf(in[(size_t)k * N + n0 + tx]);
  }
  __syncthreads();
  #pragma unroll
  for (int i = 0; i < 4; i++) {
    int n = n0 + ty + i*8;
    out[(size_t)n * K + k0 + tx] = tile[tx][ty + i*8];
  }
}

// ---------------- layernorm: x [rows][1024] (f32 or bf16) -> out bf16 ----------------
template<int BF16IN>
__global__ __launch_bounds__(256) void k_layernorm(const void* __restrict__ xin,
    const float* __restrict__ g, const float* __restrict__ b,
    unsigned short* __restrict__ out)
{
  const int row = blockIdx.x;
  const int t = threadIdx.x;
  float4 v;
  if (BF16IN) {
    const ushort4 u = ((const ushort4*)((const unsigned short*)xin + (size_t)row * 1024))[t];
    v.x = bf2f(u.x); v.y = bf2f(u.y); v.z = bf2f(u.z); v.w = bf2f(u.w);
  } else {
    v = ((const float4*)((const float*)xin + (size_t)row * 1024))[t];
  }
  float s  = v.x + v.y + v.z + v.w;
  float s2 = v.x*v.x + v.y*v.y + v.z*v.z + v.w*v.w;
  #pragma unroll
  for (int m = 1; m < 64; m <<= 1) {
    s  += __shfl_xor(s,  m);
    s2 += __shfl_xor(s2, m);
  }
  __shared__ float red[2][4];
  const int wid = t >> 6, lane = t & 63;
  if (lane == 0) { red[0][wid] = s; red[1][wid] = s2; }
  __syncthreads();
  s  = red[0][0] + red[0][1] + red[0][2] + red[0][3];
  s2 = red[1][0] + red[1][1] + red[1][2] + red[1][3];
  const float mu = s * (1.0f / 1024.0f);
  const float var = s2 * (1.0f / 1024.0f) - mu * mu;
  const float rstd = rsqrtf(var + 1e-6f);
  const float4 gv = ((const float4*)g)[t];
  const float4 bv = ((const float4*)b)[t];
  ushort4 o;
  o.x = f2bf((v.x - mu) * rstd * gv.x + bv.x);
  o.y = f2bf((v.y - mu) * rstd * gv.y + bv.y);
  o.z = f2bf((v.z - mu) * rstd * gv.z + bv.z);
  o.w = f2bf((v.w - mu) * rstd * gv.w + bv.w);
  ((ushort4*)(out + (size_t)row * 1024))[t] = o;
}

// ---------------- 128x128 MFMA GEMM — m97 structure, BK=64, 4 blocks/CU ----------
// EPI 0: QKV: bn<16 -> qk (stride 2048) bf16 [Q cols (<1024) pre-scaled by
//        log2(e) so attention's softmax runs in the exp2 domain]; bn>=16 -> vT
// EPI 1: out bf16 = gelu(acc + bias)
// EPI 2: out bf16 = resid(f32) + (acc+bias)*lsg      (proj -> x1 bf16)
// EPI 3: out f32  = resid(bf16) + (acc+bias)*lsg     (fc2 -> d_out f32)
// kk-split keeps live fragments at 32 VGPR -> fits (256,4): 4 blocks/CU.
template<int EPI>
__global__ __launch_bounds__(256, 4) void k_gemm128(
    const unsigned short* __restrict__ A,
    const unsigned short* __restrict__ Bt,
    const float* __restrict__ bias,
    const void* __restrict__ resid,
    const float* __restrict__ lsg,
    void* __restrict__ outp,
    unsigned short* __restrict__ vtp,
    int M, int N, int K, int nbn)
{
  __shared__ __align__(16) unsigned short Asm[128 * 64];   // 16 KB
  __shared__ __align__(16) unsigned short Bsm[128 * 64];   // 16 KB

  const int bid = blockIdx.x;
  const int mrows = (gridDim.x >> 3) / nbn;
  const int xcd = bid & 7, l = bid >> 3;
  const int bm = xcd * mrows + (l % mrows);
  const int bn = l / mrows;

  const int t = threadIdx.x, lane = t & 63;
  const int wid = t >> 6, wm = wid >> 1, wn = wid & 1;
  const int fr = lane & 15, fg = lane >> 4;

  size_t aOf[4], bOf[4];
  int dOf[4];
  #pragma unroll
  for (int i = 0; i < 4; i++) {
    const int s = i * 256 + t;
    const int row = s >> 3, c = s & 7;
    const int cs = c ^ (row & 7);
    dOf[i] = s * 16;
    aOf[i] = ((size_t)bm * 128 + row) * K + cs * 8;
    bOf[i] = ((size_t)bn * 128 + row) * K + cs * 8;
  }

  f32x4 acc[4][4] = {};

  for (int kt = 0; kt < K; kt += 64) {
    __syncthreads();
    #pragma unroll
    for (int i = 0; i < 4; i++) gload16(A  + aOf[i] + kt, (char*)Asm + dOf[i]);
    #pragma unroll
    for (int i = 0; i < 4; i++) gload16(Bt + bOf[i] + kt, (char*)Bsm + dOf[i]);
    __syncthreads();

    #pragma unroll
    for (int kk = 0; kk < 2; kk++) {
      short8 af[4], bfv[4];
      #pragma unroll
      for (int m = 0; m < 4; m++) {
        const int row = wm * 64 + m * 16 + fr;
        af[m] = *(const short8*)((const char*)Asm + row * 128
                                 + (((kk*4 + fg) ^ (row & 7)) * 16));
      }
      #pragma unroll
      for (int n = 0; n < 4; n++) {
        const int row = wn * 64 + n * 16 + fr;
        bfv[n] = *(const short8*)((const char*)Bsm + row * 128
                                  + (((kk*4 + fg) ^ (row & 7)) * 16));
      }
      __builtin_amdgcn_s_setprio(1);
      #pragma unroll
      for (int m = 0; m < 4; m++)
        #pragma unroll
        for (int n = 0; n < 4; n++)
          acc[m][n] = MFMA16(af[m], bfv[n], acc[m][n]);
      __builtin_amdgcn_s_setprio(0);
    }
  }

  const int row0 = bm * 128 + wm * 64 + fg * 4;
  const int col0 = bn * 128 + wn * 64 + fr;
  #pragma unroll
  for (int n = 0; n < 4; n++) {
    const int col = col0 + n * 16;
    const float bcol = bias[col];
    float lscale = 0.f;
    if (EPI >= 2) lscale = lsg[col];
    #pragma unroll
    for (int m = 0; m < 4; m++) {
      #pragma unroll
      for (int r = 0; r < 4; r++) {
        const int row = row0 + m * 16 + r;
        float v = acc[m][n][r] + bcol;
        if (EPI == 0) {
          if (bn < 16) {
            // Q columns pre-scaled by log2(e) for exp2-domain softmax
            if (col < 1024) v *= 1.44269504088896340736f;
            ((unsigned short*)outp)[(size_t)row * 2048 + col] = f2bf(v);
          } else {
            const int d = col - 2048, hh = d >> 6, dd = d & 63;
            const int bb = row >> 10, nn = row & 1023;
            vtp[(((size_t)bb * 16 + hh) * 64 + dd) * 1024 + nn] = f2bf(v);
          }
        } else if (EPI == 1) {
          const float u = v * (0.7978845608f + 0.0356774081f * v * v);
          v = v * __builtin_amdgcn_rcpf(1.0f + __expf(-2.0f * u));
          ((unsigned short*)outp)[(size_t)row * N + col] = f2bf(v);
        } else if (EPI == 2) {
          const float rv = ((const float*)resid)[(size_t)row * N + col];
          ((unsigned short*)outp)[(size_t)row * N + col] = f2bf(rv + v * lscale);
        } else {
          const float rv = bf2f(((const unsigned short*)resid)[(size_t)row * N + col]);
          ((float*)outp)[(size_t)row * N + col] = rv + v * lscale;
        }
      }
    }
  }
}

// ---------------- flash attention (no 1/sqrt(d) scale; exp2-domain softmax) ----------------
// qk: [16384][2048] bf16 (Q pre-scaled by log2e) ; vT: [b][h][64][1024] ; out bf16
// S' = Q'K^T = S*log2e -> p = exp2(S' - m') == exp(S - m). Softmax scale-invariant.
// Defer-max threshold 11.5 (== 8 nats); P bounded by 2^11.5, f32 accum fine.
__global__ __launch_bounds__(512) void k_attn(const unsigned short* __restrict__ qk,
                                              const unsigned short* __restrict__ vT,
                                              unsigned short* __restrict__ out)
{
  const int bid = blockIdx.x;
  const int xcd = bid & 7, l = bid >> 3;
  const int bh = xcd * 32 + (l >> 2);
  const int qt = l & 3;
  const int b = bh >> 4, h = bh & 15;
  const int t = threadIdx.x, lane = t & 63, wid = t >> 6;
  const int fr = lane & 15, fg = lane >> 4;
  const int q0 = qt * 256 + wid * 32;

  __shared__ __align__(16) unsigned short Ksm[2][64 * 64];   // 2 x 8 KB
  __shared__ __align__(16) unsigned short Vsm[2][64 * 64];   // 2 x 8 KB
  __shared__ __align__(16) unsigned short plds[8][16][72];   // 18 KB (total 50 KB)

  const size_t qbase = (size_t)b * 1024 * 2048 + (size_t)h * 64;
  const size_t kbase = qbase + 1024;
  const size_t vbase = (size_t)bh * 64 * 1024;

  short8 qf[2][2];
  #pragma unroll
  for (int m = 0; m < 2; m++)
    #pragma unroll
    for (int kh = 0; kh < 2; kh++)
      qf[m][kh] = *(const short8*)(qk + qbase + (size_t)(q0 + m*16 + fr) * 2048
                                   + kh*32 + fg*8);

  f32x4 oacc[2][4] = {};
  float mrow[2][4], lrow[2][4];
  #pragma unroll
  for (int m = 0; m < 2; m++)
    #pragma unroll
    for (int r = 0; r < 4; r++) { mrow[m][r] = -1e30f; lrow[m][r] = 0.f; }

  const int srow = t >> 3, sc = t & 7;
  const int scs = sc ^ (srow & 7);
  const unsigned short* kSrc = qk + kbase + (size_t)srow * 2048 + scs*8;
  const unsigned short* vSrc = vT + vbase + (size_t)srow * 1024 + scs*8;

  gload16(kSrc, (char*)&Ksm[0][0] + t*16);
  gload16(vSrc, (char*)&Vsm[0][0] + t*16);
  __syncthreads();

  for (int it = 0; it < 16; ++it) {
    const int buf = it & 1;
    if (it < 15) {
      gload16(kSrc + (size_t)(it + 1) * 64 * 2048, (char*)&Ksm[buf ^ 1][0] + t*16);
      gload16(vSrc + (it + 1) * 64,                (char*)&Vsm[buf ^ 1][0] + t*16);
    }

    f32x4 sacc[2][4] = {};
    #pragma unroll
    for (int n = 0; n < 4; n++) {
      #pragma unroll
      for (int kh = 0; kh < 2; kh++) {
        const int krow = n*16 + fr;
        short8 kf = *(const short8*)&Ksm[buf][krow*64 + (((kh*4 + fg) ^ (krow & 7)) * 8)];
        sacc[0][n] = MFMA16(qf[0][kh], kf, sacc[0][n]);
        sacc[1][n] = MFMA16(qf[1][kh], kf, sacc[1][n]);
      }
    }

    short8 pf[2][2];
    #pragma unroll
    for (int m = 0; m < 2; m++) {
      float pm[4];
      #pragma unroll
      for (int r = 0; r < 4; r++)
        pm[r] = fmaxf(fmaxf(sacc[m][0][r], sacc[m][1][r]),
                      fmaxf(sacc[m][2][r], sacc[m][3][r]));
      #pragma unroll
      for (int msk = 1; msk < 16; msk <<= 1)
        #pragma unroll
        for (int r = 0; r < 4; r++) pm[r] = fmaxf(pm[r], __shfl_xor(pm[r], msk));

      // defer-max: rescale only if row max grew > 11.5 (log2 domain == 8 nats)
      int grow = 0;
      #pragma unroll
      for (int r = 0; r < 4; r++) grow |= (pm[r] > mrow[m][r] + 11.5f) ? 1 : 0;
      if (__any(grow)) {
        #pragma unroll
        for (int r = 0; r < 4; r++) {
          const float mn = fmaxf(mrow[m][r], pm[r]);
          const float corr = exp2fast(mrow[m][r] - mn);
          mrow[m][r] = mn;
          lrow[m][r] *= corr;
          #pragma unroll
          for (int d16 = 0; d16 < 4; d16++) oacc[m][d16][r] *= corr;
        }
      }

      float psum[4] = {0.f, 0.f, 0.f, 0.f};
      #pragma unroll
      for (int n = 0; n < 4; n++)
        #pragma unroll
        for (int r = 0; r < 4; r++) {
          float p = exp2fast(sacc[m][n][r] - mrow[m][r]);
          sacc[m][n][r] = p;
          psum[r] += p;
        }
      #pragma unroll
      for (int msk = 1; msk < 16; msk <<= 1)
        #pragma unroll
        for (int r = 0; r < 4; r++) psum[r] += __shfl_xor(psum[r], msk);
      #pragma unroll
      for (int r = 0; r < 4; r++) lrow[m][r] += psum[r];

      #pragma unroll
      for (int n = 0; n < 4; n++)
        #pragma unroll
        for (int r = 0; r < 4; r++)
          plds[wid][fg*4 + r][n*16 + fr] = f2bf_rn(sacc[m][n][r]);
      #pragma unroll
      for (int kh = 0; kh < 2; kh++)
        pf[m][kh] = *(const short8*)&plds[wid][fr][kh*32 + fg*8];
    }

    #pragma unroll
    for (int d16 = 0; d16 < 4; d16++) {
      #pragma unroll
      for (int kh = 0; kh < 2; kh++) {
        const int vrow = d16*16 + fr;
        short8 vf = *(const short8*)&Vsm[buf][vrow*64 + (((kh*4 + fg) ^ (vrow & 7)) * 8)];
        oacc[0][d16] = MFMA16(pf[0][kh], vf, oacc[0][d16]);
        oacc[1][d16] = MFMA16(pf[1][kh], vf, oacc[1][d16]);
      }
    }

    __syncthreads();
  }

  #pragma unroll
  for (int m = 0; m < 2; m++) {
    float inv[4];
    #pragma unroll
    for (int r = 0; r < 4; r++) inv[r] = __builtin_amdgcn_rcpf(lrow[m][r]);
    #pragma unroll
    for (int d16 = 0; d16 < 4; d16++) {
      #pragma unroll
      for (int r = 0; r < 4; r++) {
        const int qrow = q0 + m*16 + fg*4 + r;
        const int col = h*64 + d16*16 + fr;
        out[(size_t)(b * 1024 + qrow) * 1024 + col] = f2bf(oacc[m][d16][r] * inv[r]);
      }
    }
  }
}

// ---------------- host launch ----------------
extern "C" void kernel_launch(void* const* d_in, const int* in_sizes, int n_in,
                              void* d_out, int out_size, void* d_ws, size_t ws_size,
                              hipStream_t stream) {
  const float* x      = (const float*)d_in[0];
  const float* ln1_g  = (const float*)d_in[1];
  const float* ln1_b  = (const float*)d_in[2];
  const float* qkv_w  = (const float*)d_in[3];
  const float* qkv_b  = (const float*)d_in[4];
  const float* proj_w = (const float*)d_in[5];
  const float* proj_b = (const float*)d_in[6];
  const float* ls1_g  = (const float*)d_in[7];
  const float* ln2_g  = (const float*)d_in[8];
  const float* ln2_b  = (const float*)d_in[9];
  const float* fc1_w  = (const float*)d_in[10];
  const float* fc1_b  = (const float*)d_in[11];
  const float* fc2_w  = (const float*)d_in[12];
  const float* fc2_b  = (const float*)d_in[13];
  const float* ls2_g  = (const float*)d_in[14];

  char* w = (char*)d_ws;
  unsigned short* wqkvT  = (unsigned short*)(w + 0);           //  6,291,456
  unsigned short* wprojT = (unsigned short*)(w + 6291456);     //  2,097,152
  unsigned short* wfc1T  = (unsigned short*)(w + 8388608);     //  8,388,608
  unsigned short* wfc2T  = (unsigned short*)(w + 16777216);    //  8,388,608
  unsigned short* x1     = (unsigned short*)(w + 25165824);    // 33,554,432 (bf16)
  unsigned short* h1     = (unsigned short*)(w + 58720256);    // 33,554,432
  unsigned short* qkbuf  = (unsigned short*)(w + 92274688);    // 67,108,864 [16384][2048]
  unsigned short* vtbuf  = (unsigned short*)(w + 159383552);   // 33,554,432 [256][64][1024]
  unsigned short* attno  = (unsigned short*)(w + 192937984);   // 33,554,432
  unsigned short* h3     = (unsigned short*)(w + 92274688);    // 134,217,728 (overlay)

  dim3 tb32(32, 8);
  k_transpose_cast<<<dim3(3072/32, 1024/32), tb32, 0, stream>>>(qkv_w,  wqkvT, 1024, 3072);
  k_transpose_cast<<<dim3(1024/32, 1024/32), tb32, 0, stream>>>(proj_w, wprojT, 1024, 1024);
  k_transpose_cast<<<dim3(4096/32, 1024/32), tb32, 0, stream>>>(fc1_w,  wfc1T, 1024, 4096);
  k_transpose_cast<<<dim3(1024/32, 4096/32), tb32, 0, stream>>>(fc2_w,  wfc2T, 4096, 1024);

  // LN1 (f32 in)
  k_layernorm<0><<<16384, 256, 0, stream>>>(x, ln1_g, ln1_b, h1);
  // QKV = h1 @ qkv_w + qkv_b ; Q (log2e-scaled),K -> qkbuf, V -> vtbuf transposed
  k_gemm128<0><<<128*24, 256, 0, stream>>>(h1, wqkvT, qkv_b, nullptr, nullptr,
                                           qkbuf, vtbuf, 16384, 3072, 1024, 24);
  // attention (XCD-grouped bh mapping; exp2-domain softmax)
  k_attn<<<1024, 512, 0, stream>>>(qkbuf, vtbuf, attno);
  // x1(bf16) = x(f32) + (attn @ proj_w + proj_b) * ls1_g
  k_gemm128<2><<<128*8, 256, 0, stream>>>(attno, wprojT, proj_b, x, ls1_g,
                                          x1, nullptr, 16384, 1024, 1024, 8);
  // LN2 (bf16 in)
  k_layernorm<1><<<16384, 256, 0, stream>>>(x1, ln2_g, ln2_b, h1);
  // h3 = gelu(h2 @ fc1_w + fc1_b)
  k_gemm128<1><<<128*32, 256, 0, stream>>>(h1, wfc1T, fc1_b, nullptr, nullptr,
                                           h3, nullptr, 16384, 4096, 1024, 32);
  // out(f32) = x1(bf16) + (h3 @ fc2_w + fc2_b) * ls2_g
  k_gemm128<3><<<128*8, 256, 0, stream>>>(h3, wfc2T, fc2_b, x1, ls2_g,
                                          (float*)d_out, nullptr, 16384, 1024, 4096, 8);
}

// Round 18
// 738.336 us; speedup vs baseline: 2.0244x; 1.0397x over previous
//
#include <hip/hip_runtime.h>
#include <hip/hip_bf16.h>
#include <math.h>

typedef __attribute__((ext_vector_type(8))) short short8;
typedef __attribute__((ext_vector_type(4))) float f32x4;

#define MFMA16(a,b,c) __builtin_amdgcn_mfma_f32_16x16x32_bf16((a),(b),(c),0,0,0)

__device__ __forceinline__ unsigned short f2bf(float f){
  unsigned int u = __builtin_bit_cast(unsigned int, f);
  u += 0x7fffu + ((u >> 16) & 1u);
  return (unsigned short)(u >> 16);
}
__device__ __forceinline__ unsigned short f2bf_rn(float f){
  unsigned int u = __builtin_bit_cast(unsigned int, f);
  return (unsigned short)((u + 0x8000u) >> 16);
}
__device__ __forceinline__ float bf2f(unsigned short u){
  unsigned int v = ((unsigned int)u) << 16;
  return __builtin_bit_cast(float, v);
}
__device__ __forceinline__ float exp2fast(float x){
  return __builtin_amdgcn_exp2f(x);   // bare v_exp_f32 (input already in log2 domain)
}

__device__ __forceinline__ void gload16(const void* g, void* lds){
  __builtin_amdgcn_global_load_lds(
      (const __attribute__((address_space(1))) unsigned int*)g,
      (__attribute__((address_space(3))) unsigned int*)lds, 16, 0, 0);
}

// ---------------- weight transpose + cast: in [K][N] f32 -> out [N][K] bf16 ----------------
__global__ __launch_bounds__(256) void k_transpose_cast(const float* __restrict__ in,
    unsigned short* __restrict__ out, int K, int N)
{
  __shared__ unsigned short tile[32][33];
  const int tx = threadIdx.x, ty = threadIdx.y;
  const int n0 = blockIdx.x * 32, k0 = blockIdx.y * 32;
  #pragma unroll
  for (int i = 0; i < 4; i++) {
    int k = k0 + ty + i*8;
    tile[ty + i*8][tx] = f2bf(in[(size_t)k * N + n0 + tx]);
  }
  __syncthreads();
  #pragma unroll
  for (int i = 0; i < 4; i++) {
    int n = n0 + ty + i*8;
    out[(size_t)n * K + k0 + tx] = tile[tx][ty + i*8];
  }
}

// ---------------- layernorm: x [rows][1024] (f32 or bf16) -> out bf16 ----------------
template<int BF16IN>
__global__ __launch_bounds__(256) void k_layernorm(const void* __restrict__ xin,
    const float* __restrict__ g, const float* __restrict__ b,
    unsigned short* __restrict__ out)
{
  const int row = blockIdx.x;
  const int t = threadIdx.x;
  float4 v;
  if (BF16IN) {
    const ushort4 u = ((const ushort4*)((const unsigned short*)xin + (size_t)row * 1024))[t];
    v.x = bf2f(u.x); v.y = bf2f(u.y); v.z = bf2f(u.z); v.w = bf2f(u.w);
  } else {
    v = ((const float4*)((const float*)xin + (size_t)row * 1024))[t];
  }
  float s  = v.x + v.y + v.z + v.w;
  float s2 = v.x*v.x + v.y*v.y + v.z*v.z + v.w*v.w;
  #pragma unroll
  for (int m = 1; m < 64; m <<= 1) {
    s  += __shfl_xor(s,  m);
    s2 += __shfl_xor(s2, m);
  }
  __shared__ float red[2][4];
  const int wid = t >> 6, lane = t & 63;
  if (lane == 0) { red[0][wid] = s; red[1][wid] = s2; }
  __syncthreads();
  s  = red[0][0] + red[0][1] + red[0][2] + red[0][3];
  s2 = red[1][0] + red[1][1] + red[1][2] + red[1][3];
  const float mu = s * (1.0f / 1024.0f);
  const float var = s2 * (1.0f / 1024.0f) - mu * mu;
  const float rstd = rsqrtf(var + 1e-6f);
  const float4 gv = ((const float4*)g)[t];
  const float4 bv = ((const float4*)b)[t];
  ushort4 o;
  o.x = f2bf((v.x - mu) * rstd * gv.x + bv.x);
  o.y = f2bf((v.y - mu) * rstd * gv.y + bv.y);
  o.z = f2bf((v.z - mu) * rstd * gv.z + bv.z);
  o.w = f2bf((v.w - mu) * rstd * gv.w + bv.w);
  ((ushort4*)(out + (size_t)row * 1024))[t] = o;
}

// ---------------- 128x128 MFMA GEMM — m97 structure, BK=64, 4 blocks/CU ----------
// EPI 0: QKV: bn<16 -> qk (stride 2048) bf16 [Q cols (<1024) pre-scaled by
//        log2(e) so attention's softmax runs in the exp2 domain]; bn>=16 -> vT
// EPI 1: out bf16 = gelu(acc + bias)
// EPI 2: out bf16 = resid(f32) + (acc+bias)*lsg      (proj -> x1 bf16)
// EPI 3: out f32  = resid(bf16) + (acc+bias)*lsg     (fc2 -> d_out f32)
// kk-split keeps live fragments at 32 VGPR -> fits (256,4): 4 blocks/CU.
template<int EPI>
__global__ __launch_bounds__(256, 4) void k_gemm128(
    const unsigned short* __restrict__ A,
    const unsigned short* __restrict__ Bt,
    const float* __restrict__ bias,
    const void* __restrict__ resid,
    const float* __restrict__ lsg,
    void* __restrict__ outp,
    unsigned short* __restrict__ vtp,
    int M, int N, int K, int nbn)
{
  __shared__ __align__(16) unsigned short Asm[128 * 64];   // 16 KB
  __shared__ __align__(16) unsigned short Bsm[128 * 64];   // 16 KB

  const int bid = blockIdx.x;
  const int mrows = (gridDim.x >> 3) / nbn;
  const int xcd = bid & 7, l = bid >> 3;
  const int bm = xcd * mrows + (l % mrows);
  const int bn = l / mrows;

  const int t = threadIdx.x, lane = t & 63;
  const int wid = t >> 6, wm = wid >> 1, wn = wid & 1;
  const int fr = lane & 15, fg = lane >> 4;

  size_t aOf[4], bOf[4];
  int dOf[4];
  #pragma unroll
  for (int i = 0; i < 4; i++) {
    const int s = i * 256 + t;
    const int row = s >> 3, c = s & 7;
    const int cs = c ^ (row & 7);
    dOf[i] = s * 16;
    aOf[i] = ((size_t)bm * 128 + row) * K + cs * 8;
    bOf[i] = ((size_t)bn * 128 + row) * K + cs * 8;
  }

  f32x4 acc[4][4] = {};

  for (int kt = 0; kt < K; kt += 64) {
    __syncthreads();
    #pragma unroll
    for (int i = 0; i < 4; i++) gload16(A  + aOf[i] + kt, (char*)Asm + dOf[i]);
    #pragma unroll
    for (int i = 0; i < 4; i++) gload16(Bt + bOf[i] + kt, (char*)Bsm + dOf[i]);
    __syncthreads();

    #pragma unroll
    for (int kk = 0; kk < 2; kk++) {
      short8 af[4], bfv[4];
      #pragma unroll
      for (int m = 0; m < 4; m++) {
        const int row = wm * 64 + m * 16 + fr;
        af[m] = *(const short8*)((const char*)Asm + row * 128
                                 + (((kk*4 + fg) ^ (row & 7)) * 16));
      }
      #pragma unroll
      for (int n = 0; n < 4; n++) {
        const int row = wn * 64 + n * 16 + fr;
        bfv[n] = *(const short8*)((const char*)Bsm + row * 128
                                  + (((kk*4 + fg) ^ (row & 7)) * 16));
      }
      __builtin_amdgcn_s_setprio(1);
      #pragma unroll
      for (int m = 0; m < 4; m++)
        #pragma unroll
        for (int n = 0; n < 4; n++)
          acc[m][n] = MFMA16(af[m], bfv[n], acc[m][n]);
      __builtin_amdgcn_s_setprio(0);
    }
  }

  const int row0 = bm * 128 + wm * 64 + fg * 4;
  const int col0 = bn * 128 + wn * 64 + fr;
  #pragma unroll
  for (int n = 0; n < 4; n++) {
    const int col = col0 + n * 16;
    const float bcol = bias[col];
    float lscale = 0.f;
    if (EPI >= 2) lscale = lsg[col];
    #pragma unroll
    for (int m = 0; m < 4; m++) {
      #pragma unroll
      for (int r = 0; r < 4; r++) {
        const int row = row0 + m * 16 + r;
        float v = acc[m][n][r] + bcol;
        if (EPI == 0) {
          if (bn < 16) {
            // Q columns pre-scaled by log2(e) for exp2-domain softmax
            if (col < 1024) v *= 1.44269504088896340736f;
            ((unsigned short*)outp)[(size_t)row * 2048 + col] = f2bf(v);
          } else {
            const int d = col - 2048, hh = d >> 6, dd = d & 63;
            const int bb = row >> 10, nn = row & 1023;
            vtp[(((size_t)bb * 16 + hh) * 64 + dd) * 1024 + nn] = f2bf(v);
          }
        } else if (EPI == 1) {
          const float u = v * (0.7978845608f + 0.0356774081f * v * v);
          v = v * __builtin_amdgcn_rcpf(1.0f + __expf(-2.0f * u));
          ((unsigned short*)outp)[(size_t)row * N + col] = f2bf(v);
        } else if (EPI == 2) {
          const float rv = ((const float*)resid)[(size_t)row * N + col];
          ((unsigned short*)outp)[(size_t)row * N + col] = f2bf(rv + v * lscale);
        } else {
          const float rv = bf2f(((const unsigned short*)resid)[(size_t)row * N + col]);
          ((float*)outp)[(size_t)row * N + col] = rv + v * lscale;
        }
      }
    }
  }
}

// ---------------- flash attention (no 1/sqrt(d) scale; exp2-domain softmax) ----------------
// qk: [16384][2048] bf16 (Q pre-scaled by log2e) ; vT: [b][h][64][1024] ; out bf16
// r18: softmax denominator computed on the MATRIX pipe — lacc = MFMA(P, ones)
// accumulates rowsum(P) alongside PV; deletes the 32 DS-shuffle sum-reduce per
// lane per tile. Denominator uses bf16-rounded P (consistent with numerator).
__global__ __launch_bounds__(512) void k_attn(const unsigned short* __restrict__ qk,
                                              const unsigned short* __restrict__ vT,
                                              unsigned short* __restrict__ out)
{
  const int bid = blockIdx.x;
  const int xcd = bid & 7, l = bid >> 3;
  const int bh = xcd * 32 + (l >> 2);
  const int qt = l & 3;
  const int b = bh >> 4, h = bh & 15;
  const int t = threadIdx.x, lane = t & 63, wid = t >> 6;
  const int fr = lane & 15, fg = lane >> 4;
  const int q0 = qt * 256 + wid * 32;

  __shared__ __align__(16) unsigned short Ksm[2][64 * 64];   // 2 x 8 KB
  __shared__ __align__(16) unsigned short Vsm[2][64 * 64];   // 2 x 8 KB
  __shared__ __align__(16) unsigned short plds[8][16][72];   // 18 KB (total 50 KB)

  const size_t qbase = (size_t)b * 1024 * 2048 + (size_t)h * 64;
  const size_t kbase = qbase + 1024;
  const size_t vbase = (size_t)bh * 64 * 1024;

  short8 qf[2][2];
  #pragma unroll
  for (int m = 0; m < 2; m++)
    #pragma unroll
    for (int kh = 0; kh < 2; kh++)
      qf[m][kh] = *(const short8*)(qk + qbase + (size_t)(q0 + m*16 + fr) * 2048
                                   + kh*32 + fg*8);

  short8 ones;
  #pragma unroll
  for (int i = 0; i < 8; i++) ones[i] = (short)0x3F80;   // bf16 1.0

  f32x4 oacc[2][4] = {};
  f32x4 lacc[2] = {};            // rowsum(P) accumulator (softmax denominator)
  float mrow[2][4];
  #pragma unroll
  for (int m = 0; m < 2; m++)
    #pragma unroll
    for (int r = 0; r < 4; r++) mrow[m][r] = -1e30f;

  const int srow = t >> 3, sc = t & 7;
  const int scs = sc ^ (srow & 7);
  const unsigned short* kSrc = qk + kbase + (size_t)srow * 2048 + scs*8;
  const unsigned short* vSrc = vT + vbase + (size_t)srow * 1024 + scs*8;

  gload16(kSrc, (char*)&Ksm[0][0] + t*16);
  gload16(vSrc, (char*)&Vsm[0][0] + t*16);
  __syncthreads();

  for (int it = 0; it < 16; ++it) {
    const int buf = it & 1;
    if (it < 15) {
      gload16(kSrc + (size_t)(it + 1) * 64 * 2048, (char*)&Ksm[buf ^ 1][0] + t*16);
      gload16(vSrc + (it + 1) * 64,                (char*)&Vsm[buf ^ 1][0] + t*16);
    }

    f32x4 sacc[2][4] = {};
    #pragma unroll
    for (int n = 0; n < 4; n++) {
      #pragma unroll
      for (int kh = 0; kh < 2; kh++) {
        const int krow = n*16 + fr;
        short8 kf = *(const short8*)&Ksm[buf][krow*64 + (((kh*4 + fg) ^ (krow & 7)) * 8)];
        sacc[0][n] = MFMA16(qf[0][kh], kf, sacc[0][n]);
        sacc[1][n] = MFMA16(qf[1][kh], kf, sacc[1][n]);
      }
    }

    short8 pf[2][2];
    #pragma unroll
    for (int m = 0; m < 2; m++) {
      float pm[4];
      #pragma unroll
      for (int r = 0; r < 4; r++)
        pm[r] = fmaxf(fmaxf(sacc[m][0][r], sacc[m][1][r]),
                      fmaxf(sacc[m][2][r], sacc[m][3][r]));
      #pragma unroll
      for (int msk = 1; msk < 16; msk <<= 1)
        #pragma unroll
        for (int r = 0; r < 4; r++) pm[r] = fmaxf(pm[r], __shfl_xor(pm[r], msk));

      // defer-max: rescale only if row max grew > 11.5 (log2 domain == 8 nats)
      int grow = 0;
      #pragma unroll
      for (int r = 0; r < 4; r++) grow |= (pm[r] > mrow[m][r] + 11.5f) ? 1 : 0;
      if (__any(grow)) {
        #pragma unroll
        for (int r = 0; r < 4; r++) {
          const float mn = fmaxf(mrow[m][r], pm[r]);
          const float corr = exp2fast(mrow[m][r] - mn);
          mrow[m][r] = mn;
          lacc[m][r] *= corr;
          #pragma unroll
          for (int d16 = 0; d16 < 4; d16++) oacc[m][d16][r] *= corr;
        }
      }

      // P = exp2(S - m); sum handled by MFMA-with-ones below
      #pragma unroll
      for (int n = 0; n < 4; n++)
        #pragma unroll
        for (int r = 0; r < 4; r++)
          plds[wid][fg*4 + r][n*16 + fr] =
              f2bf_rn(exp2fast(sacc[m][n][r] - mrow[m][r]));
      #pragma unroll
      for (int kh = 0; kh < 2; kh++)
        pf[m][kh] = *(const short8*)&plds[wid][fr][kh*32 + fg*8];
    }

    #pragma unroll
    for (int m = 0; m < 2; m++)
      #pragma unroll
      for (int kh = 0; kh < 2; kh++)
        lacc[m] = MFMA16(pf[m][kh], ones, lacc[m]);   // denominator on matrix pipe

    #pragma unroll
    for (int d16 = 0; d16 < 4; d16++) {
      #pragma unroll
      for (int kh = 0; kh < 2; kh++) {
        const int vrow = d16*16 + fr;
        short8 vf = *(const short8*)&Vsm[buf][vrow*64 + (((kh*4 + fg) ^ (vrow & 7)) * 8)];
        oacc[0][d16] = MFMA16(pf[0][kh], vf, oacc[0][d16]);
        oacc[1][d16] = MFMA16(pf[1][kh], vf, oacc[1][d16]);
      }
    }

    __syncthreads();
  }

  #pragma unroll
  for (int m = 0; m < 2; m++) {
    float inv[4];
    #pragma unroll
    for (int r = 0; r < 4; r++) inv[r] = __builtin_amdgcn_rcpf(lacc[m][r]);
    #pragma unroll
    for (int d16 = 0; d16 < 4; d16++) {
      #pragma unroll
      for (int r = 0; r < 4; r++) {
        const int qrow = q0 + m*16 + fg*4 + r;
        const int col = h*64 + d16*16 + fr;
        out[(size_t)(b * 1024 + qrow) * 1024 + col] = f2bf(oacc[m][d16][r] * inv[r]);
      }
    }
  }
}

// ---------------- host launch ----------------
extern "C" void kernel_launch(void* const* d_in, const int* in_sizes, int n_in,
                              void* d_out, int out_size, void* d_ws, size_t ws_size,
                              hipStream_t stream) {
  const float* x      = (const float*)d_in[0];
  const float* ln1_g  = (const float*)d_in[1];
  const float* ln1_b  = (const float*)d_in[2];
  const float* qkv_w  = (const float*)d_in[3];
  const float* qkv_b  = (const float*)d_in[4];
  const float* proj_w = (const float*)d_in[5];
  const float* proj_b = (const float*)d_in[6];
  const float* ls1_g  = (const float*)d_in[7];
  const float* ln2_g  = (const float*)d_in[8];
  const float* ln2_b  = (const float*)d_in[9];
  const float* fc1_w  = (const float*)d_in[10];
  const float* fc1_b  = (const float*)d_in[11];
  const float* fc2_w  = (const float*)d_in[12];
  const float* fc2_b  = (const float*)d_in[13];
  const float* ls2_g  = (const float*)d_in[14];

  char* w = (char*)d_ws;
  unsigned short* wqkvT  = (unsigned short*)(w + 0);           //  6,291,456
  unsigned short* wprojT = (unsigned short*)(w + 6291456);     //  2,097,152
  unsigned short* wfc1T  = (unsigned short*)(w + 8388608);     //  8,388,608
  unsigned short* wfc2T  = (unsigned short*)(w + 16777216);    //  8,388,608
  unsigned short* x1     = (unsigned short*)(w + 25165824);    // 33,554,432 (bf16)
  unsigned short* h1     = (unsigned short*)(w + 58720256);    // 33,554,432
  unsigned short* qkbuf  = (unsigned short*)(w + 92274688);    // 67,108,864 [16384][2048]
  unsigned short* vtbuf  = (unsigned short*)(w + 159383552);   // 33,554,432 [256][64][1024]
  unsigned short* attno  = (unsigned short*)(w + 192937984);   // 33,554,432
  unsigned short* h3     = (unsigned short*)(w + 92274688);    // 134,217,728 (overlay)

  dim3 tb32(32, 8);
  k_transpose_cast<<<dim3(3072/32, 1024/32), tb32, 0, stream>>>(qkv_w,  wqkvT, 1024, 3072);
  k_transpose_cast<<<dim3(1024/32, 1024/32), tb32, 0, stream>>>(proj_w, wprojT, 1024, 1024);
  k_transpose_cast<<<dim3(4096/32, 1024/32), tb32, 0, stream>>>(fc1_w,  wfc1T, 1024, 4096);
  k_transpose_cast<<<dim3(1024/32, 4096/32), tb32, 0, stream>>>(fc2_w,  wfc2T, 4096, 1024);

  // LN1 (f32 in)
  k_layernorm<0><<<16384, 256, 0, stream>>>(x, ln1_g, ln1_b, h1);
  // QKV = h1 @ qkv_w + qkv_b ; Q (log2e-scaled),K -> qkbuf, V -> vtbuf transposed
  k_gemm128<0><<<128*24, 256, 0, stream>>>(h1, wqkvT, qkv_b, nullptr, nullptr,
                                           qkbuf, vtbuf, 16384, 3072, 1024, 24);
  // attention (XCD-grouped bh mapping; exp2-domain softmax)
  k_attn<<<1024, 512, 0, stream>>>(qkbuf, vtbuf, attno);
  // x1(bf16) = x(f32) + (attn @ proj_w + proj_b) * ls1_g
  k_gemm128<2><<<128*8, 256, 0, stream>>>(attno, wprojT, proj_b, x, ls1_g,
                                          x1, nullptr, 16384, 1024, 1024, 8);
  // LN2 (bf16 in)
  k_layernorm<1><<<16384, 256, 0, stream>>>(x1, ln2_g, ln2_b, h1);
  // h3 = gelu(h2 @ fc1_w + fc1_b)
  k_gemm128<1><<<128*32, 256, 0, stream>>>(h1, wfc1T, fc1_b, nullptr, nullptr,
                                           h3, nullptr, 16384, 4096, 1024, 32);
  // out(f32) = x1(bf16) + (h3 @ fc2_w + fc2_b) * ls2_g
  k_gemm128<3><<<128*8, 256, 0, stream>>>(h3, wfc2T, fc2_b, x1, ls2_g,
                                          (float*)d_out, nullptr, 16384, 1024, 4096, 8);
}